// Round 5
// baseline (6082.393 us; speedup 1.0000x reference)
//
#include <hip/hip_runtime.h>
#include <cstddef>

#define DIMC   768
#define HEADS  12
#define HD     64
#define BATCH  8
#define SEQ    4096
#define MTOK   (BATCH*SEQ)     // 32768
#define THREEC (3*DIMC)        // 2304
#define BHN    (BATCH*HEADS)   // 96
#define NCHUNK 8               // token chunks per (b,h)
#define CHTOK  (SEQ/NCHUNK)    // 512 tokens per chunk
#define EPSN   1e-12f

// ---------------------------------------------------------------------------
// Stage 1: per (b, h, chunk) block, q,k,v for 512 tokens computed ON THE FLY.
// Processes token-subtiles in PAIRS (128 tokens): per kk the thread reads
// 2 a-fragments + 3 w-fragments (5 ds_read_b128) and does 96 FMAs
// (was 4 reads / 48 FMAs) — LDS-instruction-bound ratio 2.0 -> 1.25.
// Staging writes XOR-swizzled (col ^= {0,16,8,24}[row>>3]) to kill the
// 4-way bank conflict (8-row groups x stride 68/196 ≡ 0 mod 32 banks).
// LDS: Xs0+Xs1+Ws (42.5 KB) unioned with KV (33 KB) -> 3 blocks/CU = grid/CU.
// ---------------------------------------------------------------------------
__global__ __launch_bounds__(256, 3)
void qkv_stage1(const float* __restrict__ x, const float* __restrict__ w_qkv,
                float* __restrict__ kvp, float* __restrict__ dqp,
                float* __restrict__ dkp) {
  const int bid = blockIdx.x;
  const int bh = bid >> 3, chunk = bid & 7;
  const int b = bh / HEADS, h = bh % HEADS;
  const int tid = threadIdx.x;
  const int tx = tid & 15, ty = tid >> 4;
  const int lr = tid >> 2;                       // 0..63
  const int g  = tid & 3;                        // k-row group
  const int kc = g << 3;                         // 0,8,16,24
  const int wsw = ((g & 1) << 4) | ((g & 2) << 2);  // write swizzle {0,16,8,24}

  __shared__ float smem[10624];
  float (*Xs0)[68] = (float(*)[68])(smem);          // [32][68] sub0 (GEMM)
  float (*Xs1)[68] = (float(*)[68])(smem + 2176);   // [32][68] sub1 (GEMM)
  float (*Ws)[196] = (float(*)[196])(smem + 4352);  // [32][196] q|k|v (GEMM)
  float (*KV)[132] = (float(*)[132])(smem);         // [64][132] (outer phase)

  float kv_acc[4][4] = {};
  float dq_local[4] = {}, dk_local[4] = {};

  for (int p = 0; p < 4; ++p) {
    const float* xp0 = x + (size_t)(b * SEQ + chunk * CHTOK + p * 128) * DIMC;
    float accq[2][4][4] = {}, acck[2][4][4] = {}, accv[2][4][4] = {};
    for (int k0 = 0; k0 < DIMC; k0 += 32) {
      __syncthreads();
      {  // stage X sub0: [64 tok x 32 k] transposed, swizzled
        const float* px = &xp0[(size_t)lr * DIMC + k0 + kc];
        float4 a0 = *(const float4*)px;
        float4 a1 = *(const float4*)(px + 4);
        const int c = lr ^ wsw;
        Xs0[kc+0][c] = a0.x; Xs0[kc+1][c] = a0.y; Xs0[kc+2][c] = a0.z; Xs0[kc+3][c] = a0.w;
        Xs0[kc+4][c] = a1.x; Xs0[kc+5][c] = a1.y; Xs0[kc+6][c] = a1.z; Xs0[kc+7][c] = a1.w;
      }
      {  // stage X sub1
        const float* px = &xp0[(size_t)(64 + lr) * DIMC + k0 + kc];
        float4 a0 = *(const float4*)px;
        float4 a1 = *(const float4*)(px + 4);
        const int c = lr ^ wsw;
        Xs1[kc+0][c] = a0.x; Xs1[kc+1][c] = a0.y; Xs1[kc+2][c] = a0.z; Xs1[kc+3][c] = a0.w;
        Xs1[kc+4][c] = a1.x; Xs1[kc+5][c] = a1.y; Xs1[kc+6][c] = a1.z; Xs1[kc+7][c] = a1.w;
      }
      #pragma unroll
      for (int s = 0; s < 3; ++s) {  // stage W: q,k,v sections, swizzled
        const float* wp = w_qkv + (size_t)(s * DIMC + h * HD + lr) * DIMC + k0 + kc;
        float4 w0 = *(const float4*)wp;
        float4 w1 = *(const float4*)(wp + 4);
        const int c = s * 64 + (lr ^ wsw);
        Ws[kc+0][c] = w0.x; Ws[kc+1][c] = w0.y; Ws[kc+2][c] = w0.z; Ws[kc+3][c] = w0.w;
        Ws[kc+4][c] = w1.x; Ws[kc+5][c] = w1.y; Ws[kc+6][c] = w1.z; Ws[kc+7][c] = w1.w;
      }
      __syncthreads();
      for (int kg = 0; kg < 4; ++kg) {
        const int rsw = ((kg & 1) << 4) | ((kg & 2) << 2);  // read swizzle
        const int ca = (ty << 2) ^ rsw;
        const int cb = (tx << 2) ^ rsw;
        #pragma unroll
        for (int k2 = 0; k2 < 8; ++k2) {
          const int kk = (kg << 3) + k2;
          float4 a0 = *(const float4*)&Xs0[kk][ca];
          float4 a1 = *(const float4*)&Xs1[kk][ca];
          float4 q4 = *(const float4*)&Ws[kk][cb];
          float4 k4 = *(const float4*)&Ws[kk][64 + cb];
          float4 v4 = *(const float4*)&Ws[kk][128 + cb];
          float ar0[4] = {a0.x,a0.y,a0.z,a0.w};
          float ar1[4] = {a1.x,a1.y,a1.z,a1.w};
          float qr[4]  = {q4.x,q4.y,q4.z,q4.w};
          float kr[4]  = {k4.x,k4.y,k4.z,k4.w};
          float vr[4]  = {v4.x,v4.y,v4.z,v4.w};
          #pragma unroll
          for (int i = 0; i < 4; ++i)
            #pragma unroll
            for (int j = 0; j < 4; ++j) {
              accq[0][i][j] = fmaf(ar0[i], qr[j], accq[0][i][j]);
              acck[0][i][j] = fmaf(ar0[i], kr[j], acck[0][i][j]);
              accv[0][i][j] = fmaf(ar0[i], vr[j], accv[0][i][j]);
              accq[1][i][j] = fmaf(ar1[i], qr[j], accq[1][i][j]);
              acck[1][i][j] = fmaf(ar1[i], kr[j], acck[1][i][j]);
              accv[1][i][j] = fmaf(ar1[i], vr[j], accv[1][i][j]);
            }
        }
      }
    }
    // denominators (sub order preserved -> bit-exact vs previous rounds)
    #pragma unroll
    for (int s = 0; s < 2; ++s)
      #pragma unroll
      for (int j = 0; j < 4; ++j) {
        dq_local[j] += fabsf(accq[s][0][j]) + fabsf(accq[s][1][j]) +
                       fabsf(accq[s][2][j]) + fabsf(accq[s][3][j]);
        dk_local[j] += fabsf(acck[s][0][j]) + fabsf(acck[s][1][j]) +
                       fabsf(acck[s][2][j]) + fabsf(acck[s][3][j]);
      }
    // outer product per sub (KV aliases Xs/Ws; barrier-separated)
    #pragma unroll
    for (int s = 0; s < 2; ++s) {
      __syncthreads();
      #pragma unroll
      for (int i = 0; i < 4; ++i) {
        *(float4*)&KV[(ty<<2)+i][tx<<2] =
            make_float4(acck[s][i][0], acck[s][i][1], acck[s][i][2], acck[s][i][3]);
        *(float4*)&KV[(ty<<2)+i][64+(tx<<2)] =
            make_float4(accv[s][i][0], accv[s][i][1], accv[s][i][2], accv[s][i][3]);
      }
      __syncthreads();
      for (int t = 0; t < 64; ++t) {
        float4 kk4 = *(const float4*)&KV[t][ty<<2];
        float4 vv4 = *(const float4*)&KV[t][64+(tx<<2)];
        float kr[4] = {kk4.x,kk4.y,kk4.z,kk4.w};
        float vr[4] = {vv4.x,vv4.y,vv4.z,vv4.w};
        #pragma unroll
        for (int i = 0; i < 4; ++i)
          #pragma unroll
          for (int j = 0; j < 4; ++j)
            kv_acc[i][j] = fmaf(kr[i], vr[j], kv_acc[i][j]);
      }
    }
  }
  // write kv partial
  float* ob = kvp + (size_t)bid * (HD * HD);
  #pragma unroll
  for (int i = 0; i < 4; ++i)
    *(float4*)&ob[((ty<<2)+i) * HD + (tx<<2)] =
        make_float4(kv_acc[i][0], kv_acc[i][1], kv_acc[i][2], kv_acc[i][3]);
  // reduce dq/dk across the 16 token-groups (reuse smem as scratch)
  float* red = smem;
  __syncthreads();
  #pragma unroll
  for (int j = 0; j < 4; ++j) {
    red[ty * 64 + (tx<<2) + j]        = dq_local[j];
    red[1024 + ty * 64 + (tx<<2) + j] = dk_local[j];
  }
  __syncthreads();
  if (tid < 64) {
    float s = 0.f;
    #pragma unroll
    for (int g2 = 0; g2 < 16; ++g2) s += red[g2 * 64 + tid];
    dqp[(size_t)bid * HD + tid] = s;
  } else if (tid < 128) {
    const int d = tid - 64;
    float s = 0.f;
    #pragma unroll
    for (int g2 = 0; g2 < 16; ++g2) s += red[1024 + g2 * 64 + d];
    dkp[(size_t)bid * HD + d] = s;
  }
}

// ---------------------------------------------------------------------------
// Reduce partials, fold both L1 denominators:
// kvs[bh][d][e] = (sum_c kvp) / (max(dq,eps)*max(dk,eps))
// ---------------------------------------------------------------------------
__global__ __launch_bounds__(256)
void kv_reduce(const float* __restrict__ kvp, const float* __restrict__ dqp,
               const float* __restrict__ dkp, float* __restrict__ kvs) {
  const int bh = blockIdx.x;
  const int tid = threadIdx.x;
  __shared__ float dqL[64], dkL[64];
  if (tid < 64) {
    float s = 0.f;
    #pragma unroll
    for (int c = 0; c < NCHUNK; ++c) s += dqp[((size_t)bh * NCHUNK + c) * HD + tid];
    dqL[tid] = fmaxf(s, EPSN);
  } else if (tid < 128) {
    const int d = tid - 64;
    float s = 0.f;
    #pragma unroll
    for (int c = 0; c < NCHUNK; ++c) s += dkp[((size_t)bh * NCHUNK + c) * HD + d];
    dkL[d] = fmaxf(s, EPSN);
  }
  __syncthreads();
  #pragma unroll
  for (int i = 0; i < 16; ++i) {
    const int idx = i * 256 + tid;    // 0..4095
    const int d = idx >> 6;
    float s = 0.f;
    #pragma unroll
    for (int c = 0; c < NCHUNK; ++c)
      s += kvp[((size_t)bh * NCHUNK + c) * (HD * HD) + idx];
    kvs[(size_t)bh * (HD * HD) + idx] = s / (dqL[d] * dkL[d]);
  }
}

// ---------------------------------------------------------------------------
// W2[b][h*64+d][c] = sum_e kvs[bh][d][e] * w_proj[c][h*64+e]
// grid (96 bh, 6 c-tiles), tile [64 d x 128 c], K=64
// ---------------------------------------------------------------------------
__global__ __launch_bounds__(256)
void w2_kernel(const float* __restrict__ kvs, const float* __restrict__ w_proj,
               float* __restrict__ W2) {
  const int bh = blockIdx.x;
  const int b = bh / HEADS, h = bh % HEADS;
  const int c0 = blockIdx.y * 128;
  const int tid = threadIdx.x;
  const int tx = tid & 15, ty = tid >> 4;
  __shared__ float KVe[64][68];   // [e][d]
  __shared__ float Wp[64][132];   // [e][c]
  #pragma unroll
  for (int i = 0; i < 4; ++i) {
    const int idx = i * 256 + tid;        // 0..1023
    const int d  = idx >> 4;              // 0..63
    const int e4 = (idx & 15) << 2;       // 0..60
    float4 v4 = *(const float4*)&kvs[(size_t)bh * (HD*HD) + (size_t)d * HD + e4];
    KVe[e4+0][d] = v4.x; KVe[e4+1][d] = v4.y;
    KVe[e4+2][d] = v4.z; KVe[e4+3][d] = v4.w;
  }
  {
    const int c = tid >> 1, half = tid & 1;
    #pragma unroll
    for (int j = 0; j < 8; ++j) {
      const int e = half * 32 + j * 4;
      float4 v4 = *(const float4*)&w_proj[(size_t)(c0 + c) * DIMC + h * HD + e];
      Wp[e+0][c] = v4.x; Wp[e+1][c] = v4.y; Wp[e+2][c] = v4.z; Wp[e+3][c] = v4.w;
    }
  }
  __syncthreads();
  float acc[4][8] = {};
  for (int e = 0; e < 64; ++e) {
    float4 a4 = *(const float4*)&KVe[e][ty << 2];
    float4 b0 = *(const float4*)&Wp[e][tx << 3];
    float4 b1 = *(const float4*)&Wp[e][(tx << 3) + 4];
    float ar[4] = {a4.x, a4.y, a4.z, a4.w};
    float br[8] = {b0.x,b0.y,b0.z,b0.w,b1.x,b1.y,b1.z,b1.w};
    #pragma unroll
    for (int i = 0; i < 4; ++i)
      #pragma unroll
      for (int j = 0; j < 8; ++j)
        acc[i][j] = fmaf(ar[i], br[j], acc[i][j]);
  }
  float* W2b = W2 + (size_t)b * DIMC * DIMC;
  #pragma unroll
  for (int i = 0; i < 4; ++i) {
    const size_t row = (size_t)(h * HD + (ty<<2) + i) * DIMC + c0 + (tx<<3);
    *(float4*)&W2b[row]     = make_float4(acc[i][0], acc[i][1], acc[i][2], acc[i][3]);
    *(float4*)&W2b[row + 4] = make_float4(acc[i][4], acc[i][5], acc[i][6], acc[i][7]);
  }
}

// ---------------------------------------------------------------------------
// W3[b][m][c] = sum_k w_qkv[k][m] * W2[b][k][c]   (TN GEMM, both k-major)
// grid (6 m-tiles, 6 c-tiles, 8 b), tile 128x128, BK=16
// ---------------------------------------------------------------------------
__global__ __launch_bounds__(256)
void w3_kernel(const float* __restrict__ w_qkv, const float* __restrict__ W2,
               float* __restrict__ W3) {
  const int m0 = blockIdx.x * 128, c0 = blockIdx.y * 128, b = blockIdx.z;
  const float* Bb = W2 + (size_t)b * DIMC * DIMC;
  const int tid = threadIdx.x;
  const int tx = tid & 15, ty = tid >> 4;
  const int skk = tid >> 4, sc8 = (tid & 15) << 3;
  __shared__ float As[16][132];
  __shared__ float Bs[16][132];
  float acc[8][8] = {};
  for (int k0 = 0; k0 < DIMC; k0 += 16) {
    __syncthreads();
    *(float4*)&As[skk][sc8]     = *(const float4*)&w_qkv[(size_t)(k0+skk) * DIMC + m0 + sc8];
    *(float4*)&As[skk][sc8 + 4] = *(const float4*)&w_qkv[(size_t)(k0+skk) * DIMC + m0 + sc8 + 4];
    *(float4*)&Bs[skk][sc8]     = *(const float4*)&Bb[(size_t)(k0+skk) * DIMC + c0 + sc8];
    *(float4*)&Bs[skk][sc8 + 4] = *(const float4*)&Bb[(size_t)(k0+skk) * DIMC + c0 + sc8 + 4];
    __syncthreads();
    #pragma unroll
    for (int kk = 0; kk < 16; ++kk) {
      float4 a0 = *(const float4*)&As[kk][ty << 2];
      float4 a1 = *(const float4*)&As[kk][64 + (ty << 2)];
      float4 b0 = *(const float4*)&Bs[kk][tx << 2];
      float4 b1 = *(const float4*)&Bs[kk][64 + (tx << 2)];
      float ar[8] = {a0.x,a0.y,a0.z,a0.w,a1.x,a1.y,a1.z,a1.w};
      float br[8] = {b0.x,b0.y,b0.z,b0.w,b1.x,b1.y,b1.z,b1.w};
      #pragma unroll
      for (int i = 0; i < 8; ++i)
        #pragma unroll
        for (int j = 0; j < 8; ++j)
          acc[i][j] = fmaf(ar[i], br[j], acc[i][j]);
    }
  }
  float* Cb = W3 + (size_t)b * DIMC * DIMC;
  #pragma unroll
  for (int i = 0; i < 8; ++i) {
    const int r = m0 + ((i < 4) ? ((ty<<2) + i) : (64 + (ty<<2) + i - 4));
    #pragma unroll
    for (int jh = 0; jh < 2; ++jh) {
      const int cb = c0 + jh*64 + (tx<<2);
      *(float4*)&Cb[(size_t)r * DIMC + cb] =
          make_float4(acc[i][jh*4+0], acc[i][jh*4+1], acc[i][jh*4+2], acc[i][jh*4+3]);
    }
  }
}

// ---------------------------------------------------------------------------
// out[b][n][c] = sum_m x[b][n][m] * W3[b][m][c] + bias[c]   (NN GEMM)
// grid (32 n-tiles, 6 c-tiles, 8 b), tile 128x128, BK=16
// ---------------------------------------------------------------------------
__global__ __launch_bounds__(256)
void final_gemm(const float* __restrict__ x, const float* __restrict__ W3,
                const float* __restrict__ bias, float* __restrict__ out) {
  const int n0 = blockIdx.x * 128, c0 = blockIdx.y * 128, b = blockIdx.z;
  const float* Ab = x + (size_t)b * SEQ * DIMC;
  const float* Bb = W3 + (size_t)b * DIMC * DIMC;
  float* Cb = out + (size_t)b * SEQ * DIMC;
  const int tid = threadIdx.x;
  const int tx = tid & 15, ty = tid >> 4;
  const int lr = tid >> 2, lc4 = (tid & 3) << 2;
  const int skk = tid >> 4, sc8 = (tid & 15) << 3;
  __shared__ float As[16][132];
  __shared__ float Bs[16][132];
  float acc[8][8] = {};
  for (int k0 = 0; k0 < DIMC; k0 += 16) {
    __syncthreads();
    #pragma unroll
    for (int half = 0; half < 2; ++half) {
      const int r = lr + half * 64;
      float4 v4 = *(const float4*)&Ab[(size_t)(n0 + r) * DIMC + k0 + lc4];
      As[lc4+0][r] = v4.x; As[lc4+1][r] = v4.y;
      As[lc4+2][r] = v4.z; As[lc4+3][r] = v4.w;
    }
    *(float4*)&Bs[skk][sc8]     = *(const float4*)&Bb[(size_t)(k0+skk) * DIMC + c0 + sc8];
    *(float4*)&Bs[skk][sc8 + 4] = *(const float4*)&Bb[(size_t)(k0+skk) * DIMC + c0 + sc8 + 4];
    __syncthreads();
    #pragma unroll
    for (int kk = 0; kk < 16; ++kk) {
      float4 a0 = *(const float4*)&As[kk][ty << 2];
      float4 a1 = *(const float4*)&As[kk][64 + (ty << 2)];
      float4 b0 = *(const float4*)&Bs[kk][tx << 2];
      float4 b1 = *(const float4*)&Bs[kk][64 + (tx << 2)];
      float ar[8] = {a0.x,a0.y,a0.z,a0.w,a1.x,a1.y,a1.z,a1.w};
      float br[8] = {b0.x,b0.y,b0.z,b0.w,b1.x,b1.y,b1.z,b1.w};
      #pragma unroll
      for (int i = 0; i < 8; ++i)
        #pragma unroll
        for (int j = 0; j < 8; ++j)
          acc[i][j] = fmaf(ar[i], br[j], acc[i][j]);
    }
  }
  #pragma unroll
  for (int i = 0; i < 8; ++i) {
    const int r = n0 + ((i < 4) ? ((ty<<2) + i) : (64 + (ty<<2) + i - 4));
    #pragma unroll
    for (int jh = 0; jh < 2; ++jh) {
      const int cb = c0 + jh*64 + (tx<<2);
      float4 bv = *(const float4*)&bias[cb];
      *(float4*)&Cb[(size_t)r * DIMC + cb] =
          make_float4(acc[i][jh*4+0] + bv.x, acc[i][jh*4+1] + bv.y,
                      acc[i][jh*4+2] + bv.z, acc[i][jh*4+3] + bv.w);
    }
  }
}

// ---------------------------------------------------------------------------
extern "C" void kernel_launch(void* const* d_in, const int* in_sizes, int n_in,
                              void* d_out, int out_size, void* d_ws, size_t ws_size,
                              hipStream_t stream) {
  const float* x      = (const float*)d_in[0];
  const float* w_qkv  = (const float*)d_in[1];
  const float* w_proj = (const float*)d_in[2];
  const float* b_proj = (const float*)d_in[3];
  float* out = (float*)d_out;
  float* ws  = (float*)d_ws;

  // workspace layout (floats)
  const size_t KVP_SZ = (size_t)BHN * NCHUNK * HD * HD;  // 3,145,728
  const size_t DQP_SZ = (size_t)BHN * NCHUNK * HD;       // 49,152
  const size_t KVS_SZ = (size_t)BHN * HD * HD;           // 393,216
  const size_t W_SZ   = (size_t)BATCH * DIMC * DIMC;     // 4,718,592
  float* kvp = ws;
  float* dqp = kvp + KVP_SZ;
  float* dkp = dqp + DQP_SZ;
  float* kvs = dkp + DQP_SZ;
  float* W2  = kvs + KVS_SZ;
  float* W3  = W2 + W_SZ;
  const size_t need_bytes = (KVP_SZ + 2*DQP_SZ + KVS_SZ + 2*W_SZ) * sizeof(float);
  if (ws_size < need_bytes) return;   // clean validation failure, not a core dump

  const dim3 blk(256);
  qkv_stage1<<<dim3(BHN * NCHUNK), blk, 0, stream>>>(x, w_qkv, kvp, dqp, dkp);
  kv_reduce<<<dim3(BHN), blk, 0, stream>>>(kvp, dqp, dkp, kvs);
  w2_kernel<<<dim3(BHN, DIMC/128), blk, 0, stream>>>(kvs, w_proj, W2);
  w3_kernel<<<dim3(DIMC/128, DIMC/128, BATCH), blk, 0, stream>>>(w_qkv, W2, W3);
  final_gemm<<<dim3(SEQ/128, DIMC/128, BATCH), blk, 0, stream>>>(x, W3, b_proj, out);
}

// Round 6
// 1887.857 us; speedup vs baseline: 3.2219x; 3.2219x over previous
//
#include <hip/hip_runtime.h>
#include <cstddef>

#define DIMC   768
#define HEADS  12
#define HD     64
#define BATCH  8
#define SEQ    4096
#define MTOK   (BATCH*SEQ)     // 32768
#define THREEC (3*DIMC)        // 2304
#define BHN    (BATCH*HEADS)   // 96
#define NCHUNK 8               // token chunks per (b,h)
#define CHTOK  (SEQ/NCHUNK)    // 512 tokens per chunk
#define EPSN   1e-12f

// ---------------------------------------------------------------------------
// Stage 1: per (b, h, chunk) block, q,k,v for 512 tokens computed ON THE FLY.
// Token-subtiles processed in PAIRS: per kk, 5 ds_read_b128 feed 96 FMAs.
// Staging writes XOR-swizzled (col ^= {0,16,8,24}[row>>3]) -> 0 bank conflicts
// (verified R5). launch_bounds(256,2): VGPR cap 256 — the paired tile needs
// ~150 VGPR; R5's (256,3) cap forced spill-to-scratch (14.9 GB HBM writes).
// ---------------------------------------------------------------------------
__global__ __launch_bounds__(256, 2)
void qkv_stage1(const float* __restrict__ x, const float* __restrict__ w_qkv,
                float* __restrict__ kvp, float* __restrict__ dqp,
                float* __restrict__ dkp) {
  const int bid = blockIdx.x;
  const int bh = bid >> 3, chunk = bid & 7;
  const int b = bh / HEADS, h = bh % HEADS;
  const int tid = threadIdx.x;
  const int tx = tid & 15, ty = tid >> 4;
  const int lr = tid >> 2;                       // 0..63
  const int g  = tid & 3;                        // k-row group
  const int kc = g << 3;                         // 0,8,16,24
  const int wsw = ((g & 1) << 4) | ((g & 2) << 2);  // write swizzle {0,16,8,24}

  __shared__ float smem[10624];
  float (*Xs0)[68] = (float(*)[68])(smem);          // [32][68] sub0 (GEMM)
  float (*Xs1)[68] = (float(*)[68])(smem + 2176);   // [32][68] sub1 (GEMM)
  float (*Ws)[196] = (float(*)[196])(smem + 4352);  // [32][196] q|k|v (GEMM)
  float (*KV)[132] = (float(*)[132])(smem);         // [64][132] (outer phase)

  float kv_acc[4][4] = {};
  float dq_local[4] = {}, dk_local[4] = {};

  for (int p = 0; p < 4; ++p) {
    const float* xp0 = x + (size_t)(b * SEQ + chunk * CHTOK + p * 128) * DIMC;
    float accq[2][4][4] = {}, acck[2][4][4] = {}, accv[2][4][4] = {};
    for (int k0 = 0; k0 < DIMC; k0 += 32) {
      __syncthreads();
      {  // stage X sub0: [64 tok x 32 k] transposed, swizzled
        const float* px = &xp0[(size_t)lr * DIMC + k0 + kc];
        float4 a0 = *(const float4*)px;
        float4 a1 = *(const float4*)(px + 4);
        const int c = lr ^ wsw;
        Xs0[kc+0][c] = a0.x; Xs0[kc+1][c] = a0.y; Xs0[kc+2][c] = a0.z; Xs0[kc+3][c] = a0.w;
        Xs0[kc+4][c] = a1.x; Xs0[kc+5][c] = a1.y; Xs0[kc+6][c] = a1.z; Xs0[kc+7][c] = a1.w;
      }
      {  // stage X sub1
        const float* px = &xp0[(size_t)(64 + lr) * DIMC + k0 + kc];
        float4 a0 = *(const float4*)px;
        float4 a1 = *(const float4*)(px + 4);
        const int c = lr ^ wsw;
        Xs1[kc+0][c] = a0.x; Xs1[kc+1][c] = a0.y; Xs1[kc+2][c] = a0.z; Xs1[kc+3][c] = a0.w;
        Xs1[kc+4][c] = a1.x; Xs1[kc+5][c] = a1.y; Xs1[kc+6][c] = a1.z; Xs1[kc+7][c] = a1.w;
      }
      #pragma unroll
      for (int s = 0; s < 3; ++s) {  // stage W: q,k,v sections, swizzled
        const float* wp = w_qkv + (size_t)(s * DIMC + h * HD + lr) * DIMC + k0 + kc;
        float4 w0 = *(const float4*)wp;
        float4 w1 = *(const float4*)(wp + 4);
        const int c = s * 64 + (lr ^ wsw);
        Ws[kc+0][c] = w0.x; Ws[kc+1][c] = w0.y; Ws[kc+2][c] = w0.z; Ws[kc+3][c] = w0.w;
        Ws[kc+4][c] = w1.x; Ws[kc+5][c] = w1.y; Ws[kc+6][c] = w1.z; Ws[kc+7][c] = w1.w;
      }
      __syncthreads();
      for (int kg = 0; kg < 4; ++kg) {
        const int rsw = ((kg & 1) << 4) | ((kg & 2) << 2);  // read swizzle
        const int ca = (ty << 2) ^ rsw;
        const int cb = (tx << 2) ^ rsw;
        #pragma unroll
        for (int k2 = 0; k2 < 8; ++k2) {
          const int kk = (kg << 3) + k2;
          float4 a0 = *(const float4*)&Xs0[kk][ca];
          float4 a1 = *(const float4*)&Xs1[kk][ca];
          float4 q4 = *(const float4*)&Ws[kk][cb];
          float4 k4 = *(const float4*)&Ws[kk][64 + cb];
          float4 v4 = *(const float4*)&Ws[kk][128 + cb];
          float ar0[4] = {a0.x,a0.y,a0.z,a0.w};
          float ar1[4] = {a1.x,a1.y,a1.z,a1.w};
          float qr[4]  = {q4.x,q4.y,q4.z,q4.w};
          float kr[4]  = {k4.x,k4.y,k4.z,k4.w};
          float vr[4]  = {v4.x,v4.y,v4.z,v4.w};
          #pragma unroll
          for (int i = 0; i < 4; ++i)
            #pragma unroll
            for (int j = 0; j < 4; ++j) {
              accq[0][i][j] = fmaf(ar0[i], qr[j], accq[0][i][j]);
              acck[0][i][j] = fmaf(ar0[i], kr[j], acck[0][i][j]);
              accv[0][i][j] = fmaf(ar0[i], vr[j], accv[0][i][j]);
              accq[1][i][j] = fmaf(ar1[i], qr[j], accq[1][i][j]);
              acck[1][i][j] = fmaf(ar1[i], kr[j], acck[1][i][j]);
              accv[1][i][j] = fmaf(ar1[i], vr[j], accv[1][i][j]);
            }
        }
      }
    }
    // denominators (sub order preserved -> bit-exact vs previous rounds)
    #pragma unroll
    for (int s = 0; s < 2; ++s)
      #pragma unroll
      for (int j = 0; j < 4; ++j) {
        dq_local[j] += fabsf(accq[s][0][j]) + fabsf(accq[s][1][j]) +
                       fabsf(accq[s][2][j]) + fabsf(accq[s][3][j]);
        dk_local[j] += fabsf(acck[s][0][j]) + fabsf(acck[s][1][j]) +
                       fabsf(acck[s][2][j]) + fabsf(acck[s][3][j]);
      }
    // outer product per sub (KV aliases Xs/Ws; barrier-separated)
    #pragma unroll
    for (int s = 0; s < 2; ++s) {
      __syncthreads();
      #pragma unroll
      for (int i = 0; i < 4; ++i) {
        *(float4*)&KV[(ty<<2)+i][tx<<2] =
            make_float4(acck[s][i][0], acck[s][i][1], acck[s][i][2], acck[s][i][3]);
        *(float4*)&KV[(ty<<2)+i][64+(tx<<2)] =
            make_float4(accv[s][i][0], accv[s][i][1], accv[s][i][2], accv[s][i][3]);
      }
      __syncthreads();
      for (int t = 0; t < 64; ++t) {
        float4 kk4 = *(const float4*)&KV[t][ty<<2];
        float4 vv4 = *(const float4*)&KV[t][64+(tx<<2)];
        float kr[4] = {kk4.x,kk4.y,kk4.z,kk4.w};
        float vr[4] = {vv4.x,vv4.y,vv4.z,vv4.w};
        #pragma unroll
        for (int i = 0; i < 4; ++i)
          #pragma unroll
          for (int j = 0; j < 4; ++j)
            kv_acc[i][j] = fmaf(kr[i], vr[j], kv_acc[i][j]);
      }
    }
  }
  // write kv partial
  float* ob = kvp + (size_t)bid * (HD * HD);
  #pragma unroll
  for (int i = 0; i < 4; ++i)
    *(float4*)&ob[((ty<<2)+i) * HD + (tx<<2)] =
        make_float4(kv_acc[i][0], kv_acc[i][1], kv_acc[i][2], kv_acc[i][3]);
  // reduce dq/dk across the 16 token-groups (reuse smem as scratch)
  float* red = smem;
  __syncthreads();
  #pragma unroll
  for (int j = 0; j < 4; ++j) {
    red[ty * 64 + (tx<<2) + j]        = dq_local[j];
    red[1024 + ty * 64 + (tx<<2) + j] = dk_local[j];
  }
  __syncthreads();
  if (tid < 64) {
    float s = 0.f;
    #pragma unroll
    for (int g2 = 0; g2 < 16; ++g2) s += red[g2 * 64 + tid];
    dqp[(size_t)bid * HD + tid] = s;
  } else if (tid < 128) {
    const int d = tid - 64;
    float s = 0.f;
    #pragma unroll
    for (int g2 = 0; g2 < 16; ++g2) s += red[1024 + g2 * 64 + d];
    dkp[(size_t)bid * HD + d] = s;
  }
}

// ---------------------------------------------------------------------------
// Reduce partials, fold both L1 denominators:
// kvs[bh][d][e] = (sum_c kvp) / (max(dq,eps)*max(dk,eps))
// ---------------------------------------------------------------------------
__global__ __launch_bounds__(256)
void kv_reduce(const float* __restrict__ kvp, const float* __restrict__ dqp,
               const float* __restrict__ dkp, float* __restrict__ kvs) {
  const int bh = blockIdx.x;
  const int tid = threadIdx.x;
  __shared__ float dqL[64], dkL[64];
  if (tid < 64) {
    float s = 0.f;
    #pragma unroll
    for (int c = 0; c < NCHUNK; ++c) s += dqp[((size_t)bh * NCHUNK + c) * HD + tid];
    dqL[tid] = fmaxf(s, EPSN);
  } else if (tid < 128) {
    const int d = tid - 64;
    float s = 0.f;
    #pragma unroll
    for (int c = 0; c < NCHUNK; ++c) s += dkp[((size_t)bh * NCHUNK + c) * HD + d];
    dkL[d] = fmaxf(s, EPSN);
  }
  __syncthreads();
  #pragma unroll
  for (int i = 0; i < 16; ++i) {
    const int idx = i * 256 + tid;    // 0..4095
    const int d = idx >> 6;
    float s = 0.f;
    #pragma unroll
    for (int c = 0; c < NCHUNK; ++c)
      s += kvp[((size_t)bh * NCHUNK + c) * (HD * HD) + idx];
    kvs[(size_t)bh * (HD * HD) + idx] = s / (dqL[d] * dkL[d]);
  }
}

// ---------------------------------------------------------------------------
// W2[b][h*64+d][c] = sum_e kvs[bh][d][e] * w_proj[c][h*64+e]
// grid (96 bh, 6 c-tiles), tile [64 d x 128 c], K=64
// ---------------------------------------------------------------------------
__global__ __launch_bounds__(256)
void w2_kernel(const float* __restrict__ kvs, const float* __restrict__ w_proj,
               float* __restrict__ W2) {
  const int bh = blockIdx.x;
  const int b = bh / HEADS, h = bh % HEADS;
  const int c0 = blockIdx.y * 128;
  const int tid = threadIdx.x;
  const int tx = tid & 15, ty = tid >> 4;
  __shared__ float KVe[64][68];   // [e][d]
  __shared__ float Wp[64][132];   // [e][c]
  #pragma unroll
  for (int i = 0; i < 4; ++i) {
    const int idx = i * 256 + tid;        // 0..1023
    const int d  = idx >> 4;              // 0..63
    const int e4 = (idx & 15) << 2;       // 0..60
    float4 v4 = *(const float4*)&kvs[(size_t)bh * (HD*HD) + (size_t)d * HD + e4];
    KVe[e4+0][d] = v4.x; KVe[e4+1][d] = v4.y;
    KVe[e4+2][d] = v4.z; KVe[e4+3][d] = v4.w;
  }
  {
    const int c = tid >> 1, half = tid & 1;
    #pragma unroll
    for (int j = 0; j < 8; ++j) {
      const int e = half * 32 + j * 4;
      float4 v4 = *(const float4*)&w_proj[(size_t)(c0 + c) * DIMC + h * HD + e];
      Wp[e+0][c] = v4.x; Wp[e+1][c] = v4.y; Wp[e+2][c] = v4.z; Wp[e+3][c] = v4.w;
    }
  }
  __syncthreads();
  float acc[4][8] = {};
  for (int e = 0; e < 64; ++e) {
    float4 a4 = *(const float4*)&KVe[e][ty << 2];
    float4 b0 = *(const float4*)&Wp[e][tx << 3];
    float4 b1 = *(const float4*)&Wp[e][(tx << 3) + 4];
    float ar[4] = {a4.x, a4.y, a4.z, a4.w};
    float br[8] = {b0.x,b0.y,b0.z,b0.w,b1.x,b1.y,b1.z,b1.w};
    #pragma unroll
    for (int i = 0; i < 4; ++i)
      #pragma unroll
      for (int j = 0; j < 8; ++j)
        acc[i][j] = fmaf(ar[i], br[j], acc[i][j]);
  }
  float* W2b = W2 + (size_t)b * DIMC * DIMC;
  #pragma unroll
  for (int i = 0; i < 4; ++i) {
    const size_t row = (size_t)(h * HD + (ty<<2) + i) * DIMC + c0 + (tx<<3);
    *(float4*)&W2b[row]     = make_float4(acc[i][0], acc[i][1], acc[i][2], acc[i][3]);
    *(float4*)&W2b[row + 4] = make_float4(acc[i][4], acc[i][5], acc[i][6], acc[i][7]);
  }
}

// ---------------------------------------------------------------------------
// W3[b][m][c] = sum_k w_qkv[k][m] * W2[b][k][c]   (TN GEMM, both k-major)
// grid (6 m-tiles, 6 c-tiles, 8 b), tile 128x128, BK=16
// ---------------------------------------------------------------------------
__global__ __launch_bounds__(256)
void w3_kernel(const float* __restrict__ w_qkv, const float* __restrict__ W2,
               float* __restrict__ W3) {
  const int m0 = blockIdx.x * 128, c0 = blockIdx.y * 128, b = blockIdx.z;
  const float* Bb = W2 + (size_t)b * DIMC * DIMC;
  const int tid = threadIdx.x;
  const int tx = tid & 15, ty = tid >> 4;
  const int skk = tid >> 4, sc8 = (tid & 15) << 3;
  __shared__ float As[16][132];
  __shared__ float Bs[16][132];
  float acc[8][8] = {};
  for (int k0 = 0; k0 < DIMC; k0 += 16) {
    __syncthreads();
    *(float4*)&As[skk][sc8]     = *(const float4*)&w_qkv[(size_t)(k0+skk) * DIMC + m0 + sc8];
    *(float4*)&As[skk][sc8 + 4] = *(const float4*)&w_qkv[(size_t)(k0+skk) * DIMC + m0 + sc8 + 4];
    *(float4*)&Bs[skk][sc8]     = *(const float4*)&Bb[(size_t)(k0+skk) * DIMC + c0 + sc8];
    *(float4*)&Bs[skk][sc8 + 4] = *(const float4*)&Bb[(size_t)(k0+skk) * DIMC + c0 + sc8 + 4];
    __syncthreads();
    #pragma unroll
    for (int kk = 0; kk < 16; ++kk) {
      float4 a0 = *(const float4*)&As[kk][ty << 2];
      float4 a1 = *(const float4*)&As[kk][64 + (ty << 2)];
      float4 b0 = *(const float4*)&Bs[kk][tx << 2];
      float4 b1 = *(const float4*)&Bs[kk][64 + (tx << 2)];
      float ar[8] = {a0.x,a0.y,a0.z,a0.w,a1.x,a1.y,a1.z,a1.w};
      float br[8] = {b0.x,b0.y,b0.z,b0.w,b1.x,b1.y,b1.z,b1.w};
      #pragma unroll
      for (int i = 0; i < 8; ++i)
        #pragma unroll
        for (int j = 0; j < 8; ++j)
          acc[i][j] = fmaf(ar[i], br[j], acc[i][j]);
    }
  }
  float* Cb = W3 + (size_t)b * DIMC * DIMC;
  #pragma unroll
  for (int i = 0; i < 8; ++i) {
    const int r = m0 + ((i < 4) ? ((ty<<2) + i) : (64 + (ty<<2) + i - 4));
    #pragma unroll
    for (int jh = 0; jh < 2; ++jh) {
      const int cb = c0 + jh*64 + (tx<<2);
      *(float4*)&Cb[(size_t)r * DIMC + cb] =
          make_float4(acc[i][jh*4+0], acc[i][jh*4+1], acc[i][jh*4+2], acc[i][jh*4+3]);
    }
  }
}

// ---------------------------------------------------------------------------
// out[b][n][c] = sum_m x[b][n][m] * W3[b][m][c] + bias[c]   (NN GEMM)
// grid (32 n-tiles, 6 c-tiles, 8 b), tile 128x128, BK=16
// ---------------------------------------------------------------------------
__global__ __launch_bounds__(256)
void final_gemm(const float* __restrict__ x, const float* __restrict__ W3,
                const float* __restrict__ bias, float* __restrict__ out) {
  const int n0 = blockIdx.x * 128, c0 = blockIdx.y * 128, b = blockIdx.z;
  const float* Ab = x + (size_t)b * SEQ * DIMC;
  const float* Bb = W3 + (size_t)b * DIMC * DIMC;
  float* Cb = out + (size_t)b * SEQ * DIMC;
  const int tid = threadIdx.x;
  const int tx = tid & 15, ty = tid >> 4;
  const int lr = tid >> 2, lc4 = (tid & 3) << 2;
  const int skk = tid >> 4, sc8 = (tid & 15) << 3;
  __shared__ float As[16][132];
  __shared__ float Bs[16][132];
  float acc[8][8] = {};
  for (int k0 = 0; k0 < DIMC; k0 += 16) {
    __syncthreads();
    #pragma unroll
    for (int half = 0; half < 2; ++half) {
      const int r = lr + half * 64;
      float4 v4 = *(const float4*)&Ab[(size_t)(n0 + r) * DIMC + k0 + lc4];
      As[lc4+0][r] = v4.x; As[lc4+1][r] = v4.y;
      As[lc4+2][r] = v4.z; As[lc4+3][r] = v4.w;
    }
    *(float4*)&Bs[skk][sc8]     = *(const float4*)&Bb[(size_t)(k0+skk) * DIMC + c0 + sc8];
    *(float4*)&Bs[skk][sc8 + 4] = *(const float4*)&Bb[(size_t)(k0+skk) * DIMC + c0 + sc8 + 4];
    __syncthreads();
    #pragma unroll
    for (int kk = 0; kk < 16; ++kk) {
      float4 a0 = *(const float4*)&As[kk][ty << 2];
      float4 a1 = *(const float4*)&As[kk][64 + (ty << 2)];
      float4 b0 = *(const float4*)&Bs[kk][tx << 2];
      float4 b1 = *(const float4*)&Bs[kk][64 + (tx << 2)];
      float ar[8] = {a0.x,a0.y,a0.z,a0.w,a1.x,a1.y,a1.z,a1.w};
      float br[8] = {b0.x,b0.y,b0.z,b0.w,b1.x,b1.y,b1.z,b1.w};
      #pragma unroll
      for (int i = 0; i < 8; ++i)
        #pragma unroll
        for (int j = 0; j < 8; ++j)
          acc[i][j] = fmaf(ar[i], br[j], acc[i][j]);
    }
  }
  #pragma unroll
  for (int i = 0; i < 8; ++i) {
    const int r = n0 + ((i < 4) ? ((ty<<2) + i) : (64 + (ty<<2) + i - 4));
    #pragma unroll
    for (int jh = 0; jh < 2; ++jh) {
      const int cb = c0 + jh*64 + (tx<<2);
      float4 bv = *(const float4*)&bias[cb];
      *(float4*)&Cb[(size_t)r * DIMC + cb] =
          make_float4(acc[i][jh*4+0] + bv.x, acc[i][jh*4+1] + bv.y,
                      acc[i][jh*4+2] + bv.z, acc[i][jh*4+3] + bv.w);
    }
  }
}

// ---------------------------------------------------------------------------
extern "C" void kernel_launch(void* const* d_in, const int* in_sizes, int n_in,
                              void* d_out, int out_size, void* d_ws, size_t ws_size,
                              hipStream_t stream) {
  const float* x      = (const float*)d_in[0];
  const float* w_qkv  = (const float*)d_in[1];
  const float* w_proj = (const float*)d_in[2];
  const float* b_proj = (const float*)d_in[3];
  float* out = (float*)d_out;
  float* ws  = (float*)d_ws;

  // workspace layout (floats)
  const size_t KVP_SZ = (size_t)BHN * NCHUNK * HD * HD;  // 3,145,728
  const size_t DQP_SZ = (size_t)BHN * NCHUNK * HD;       // 49,152
  const size_t KVS_SZ = (size_t)BHN * HD * HD;           // 393,216
  const size_t W_SZ   = (size_t)BATCH * DIMC * DIMC;     // 4,718,592
  float* kvp = ws;
  float* dqp = kvp + KVP_SZ;
  float* dkp = dqp + DQP_SZ;
  float* kvs = dkp + DQP_SZ;
  float* W2  = kvs + KVS_SZ;
  float* W3  = W2 + W_SZ;
  const size_t need_bytes = (KVP_SZ + 2*DQP_SZ + KVS_SZ + 2*W_SZ) * sizeof(float);
  if (ws_size < need_bytes) return;   // clean validation failure, not a core dump

  const dim3 blk(256);
  qkv_stage1<<<dim3(BHN * NCHUNK), blk, 0, stream>>>(x, w_qkv, kvp, dqp, dkp);
  kv_reduce<<<dim3(BHN), blk, 0, stream>>>(kvp, dqp, dkp, kvs);
  w2_kernel<<<dim3(BHN, DIMC/128), blk, 0, stream>>>(kvs, w_proj, W2);
  w3_kernel<<<dim3(DIMC/128, DIMC/128, BATCH), blk, 0, stream>>>(w_qkv, W2, W3);
  final_gemm<<<dim3(SEQ/128, DIMC/128, BATCH), blk, 0, stream>>>(x, W3, b_proj, out);
}

// Round 7
// 1769.096 us; speedup vs baseline: 3.4381x; 1.0671x over previous
//
#include <hip/hip_runtime.h>
#include <cstddef>
#include <cstdint>

#define DIMC   768
#define HEADS  12
#define HD     64
#define BATCH  8
#define SEQ    4096
#define MTOK   (BATCH*SEQ)     // 32768
#define THREEC (3*DIMC)        // 2304
#define BHN    (BATCH*HEADS)   // 96
#define NCHUNK 8               // token chunks per (b,h)
#define CHTOK  (SEQ/NCHUNK)    // 512 tokens per chunk
#define EPSN   1e-12f

typedef unsigned short u16;
typedef unsigned int   u32;
typedef __attribute__((ext_vector_type(8))) short short8;   // 8 bf16 (4 VGPR)
typedef __attribute__((ext_vector_type(4))) float f32x4;

// ---------------------------------------------------------------------------
// Split fp32 -> bf16 hi/lo pairs, interleaved per 8-element group:
// out group g (8 elems): [hi0..hi7][lo0..lo7]  (32 B per group)
// hi = RNE(bf16(x)); lo = RNE(bf16(x - hi))  -> x = hi+lo to ~2^-18 rel.
// ---------------------------------------------------------------------------
__device__ inline u16 bf16_rne(float f) {
  u32 u = __float_as_uint(f);
  u32 r = u + 0x7fffu + ((u >> 16) & 1u);
  return (u16)(r >> 16);
}

__global__ __launch_bounds__(256)
void split_bf16(const float* __restrict__ in, u16* __restrict__ outp, int ngroups) {
  for (int g = blockIdx.x * 256 + threadIdx.x; g < ngroups; g += gridDim.x * 256) {
    float4 x0 = *(const float4*)(in + (size_t)g * 8);
    float4 x1 = *(const float4*)(in + (size_t)g * 8 + 4);
    float xs[8] = {x0.x, x0.y, x0.z, x0.w, x1.x, x1.y, x1.z, x1.w};
    u32 hw[4], lw[4];
    #pragma unroll
    for (int i = 0; i < 4; ++i) {
      u16 h0 = bf16_rne(xs[2*i]);
      u16 h1 = bf16_rne(xs[2*i+1]);
      float r0 = xs[2*i]   - __uint_as_float(((u32)h0) << 16);
      float r1 = xs[2*i+1] - __uint_as_float(((u32)h1) << 16);
      u16 l0 = bf16_rne(r0);
      u16 l1 = bf16_rne(r1);
      hw[i] = (u32)h0 | ((u32)h1 << 16);
      lw[i] = (u32)l0 | ((u32)l1 << 16);
    }
    uint4* dst = (uint4*)(outp + (size_t)g * 16);
    dst[0] = make_uint4(hw[0], hw[1], hw[2], hw[3]);
    dst[1] = make_uint4(lw[0], lw[1], lw[2], lw[3]);
  }
}

// ---------------------------------------------------------------------------
// Stage 1 (MFMA bf16x3): per (b, h, chunk) block, q,k,v for 512 tokens
// computed on the fly via mfma_f32_16x16x32_bf16 with hi/lo split
// (hh + hl + lh products -> ~2^-17 rel precision, fp32 accumulate).
// Per 64-token sub: 4 waves x (4 tok-tiles x 3 out-tiles of 16).
// LDS tiles: 128B rows of 8x16B pieces XOR-swizzled by (row&7) -> 2-way
// (free) ds_read_b128 on fragment reads. Xs 8KB + Ws 24KB unioned with
// fp32 KV[64][132] (33.8KB) for the outer-product phase.
// |q|,|k| sums and kv outer product stay fp32 (error contribution ~0).
// ---------------------------------------------------------------------------
__global__ __launch_bounds__(256)
void qkv_stage1(const u16* __restrict__ xc, const u16* __restrict__ wc,
                float* __restrict__ kvp, float* __restrict__ dqp,
                float* __restrict__ dkp) {
  const int bid = blockIdx.x;
  const int h = bid % HEADS;          // 12 consecutive blocks share one x-slice
  const int bc = bid / HEADS;
  const int b = bc >> 3, chunk = bc & 7;
  const int bh = b * HEADS + h;
  const int si = bh * NCHUNK + chunk; // storage index (layout as before)

  const int tid = threadIdx.x;
  const int w = tid >> 6, l = tid & 63;
  const int lr16 = l & 15, cg = l >> 4;
  const int tx = tid & 15, ty = tid >> 4;   // outer-product thread layout

  __shared__ __align__(16) unsigned char smem[33792];
  u16* Xs  = (u16*)smem;             // [64 rows][64 u16] = 8 KB   (GEMM)
  u16* Wsm = (u16*)(smem + 8192);    // [192 rows][64 u16] = 24 KB (GEMM)
  float (*KV)[132] = (float(*)[132])smem;   // [64][132] fp32 (outer phase)
  float* red = (float*)smem;                // 512 floats (epilogue)

  float kv_acc[4][4] = {};
  float dsum[3] = {};                 // per-ot |q| or |k| accumulation

  const size_t xrow0 = (size_t)(b * SEQ + chunk * CHTOK) * 1536;  // u16/row = 1536

  for (int sub = 0; sub < 8; ++sub) {
    const size_t xbase = xrow0 + (size_t)sub * 64 * 1536;
    f32x4 acc[4][3];
    #pragma unroll
    for (int tt = 0; tt < 4; ++tt)
      #pragma unroll
      for (int ot = 0; ot < 3; ++ot)
        acc[tt][ot] = (f32x4){0.f, 0.f, 0.f, 0.f};

    for (int k0 = 0; k0 < DIMC; k0 += 32) {
      __syncthreads();   // protect LDS from overwrite while readers active
      const int g0 = k0 >> 3;
      // stage 2048 x 16B pieces (X: 512, W: 1536); 8 per thread
      #pragma unroll
      for (int it = 0; it < 8; ++it) {
        const int pid = it * 256 + tid;
        const u16* src;
        u16* dst;
        if (pid < 512) {
          const int t = pid >> 3, s = pid & 7, p = s ^ (t & 7);
          const int off = (p < 4) ? (g0 + p) * 16 : ((g0 + p - 4) * 16 + 8);
          src = xc + xbase + (size_t)t * 1536 + off;
          dst = Xs + t * 64 + s * 8;
        } else {
          const int q = pid - 512;
          const int o = q >> 3, s = q & 7, p = s ^ (o & 7);
          const int sec = o >> 6;
          const int grow = sec * DIMC + h * HD + (o & 63);
          const int off = (p < 4) ? (g0 + p) * 16 : ((g0 + p - 4) * 16 + 8);
          src = wc + (size_t)grow * 1536 + off;
          dst = Wsm + o * 64 + s * 8;
        }
        *(uint4*)dst = *(const uint4*)src;
      }
      __syncthreads();
      // fragment reads + MFMA (bf16x3)
      short8 bh_[3], bl_[3];
      #pragma unroll
      for (int ot = 0; ot < 3; ++ot) {
        const int o = w * 48 + ot * 16 + lr16;
        const int sh = cg ^ (o & 7);
        bh_[ot] = *(const short8*)(Wsm + o * 64 + sh * 8);
        bl_[ot] = *(const short8*)(Wsm + o * 64 + (sh ^ 4) * 8);
      }
      #pragma unroll
      for (int tt = 0; tt < 4; ++tt) {
        const int t = tt * 16 + lr16;
        const int sh = cg ^ (t & 7);
        short8 ah = *(const short8*)(Xs + t * 64 + sh * 8);
        short8 al = *(const short8*)(Xs + t * 64 + (sh ^ 4) * 8);
        #pragma unroll
        for (int ot = 0; ot < 3; ++ot) {
          acc[tt][ot] = __builtin_amdgcn_mfma_f32_16x16x32_bf16(ah, bh_[ot], acc[tt][ot], 0, 0, 0);
          acc[tt][ot] = __builtin_amdgcn_mfma_f32_16x16x32_bf16(ah, bl_[ot], acc[tt][ot], 0, 0, 0);
          acc[tt][ot] = __builtin_amdgcn_mfma_f32_16x16x32_bf16(al, bh_[ot], acc[tt][ot], 0, 0, 0);
        }
      }
    }
    // C-frag (tt,ot) value r sits at row = tt*16 + (l>>4)*4 + r,
    //                            col = w*48 + ot*16 + (l&15)   [m89 layout]
    __syncthreads();   // all frag reads done -> Xs/Ws reusable as KV
    #pragma unroll
    for (int ot = 0; ot < 3; ++ot) {
      const int colbase = w * 48 + ot * 16;
      const int col = colbase + lr16;
      if (colbase < 64) {            // q: |sum| only
        #pragma unroll
        for (int tt = 0; tt < 4; ++tt)
          #pragma unroll
          for (int r = 0; r < 4; ++r)
            dsum[ot] += fabsf(acc[tt][ot][r]);
      } else if (colbase < 128) {    // k: |sum| + KV scatter
        #pragma unroll
        for (int tt = 0; tt < 4; ++tt)
          #pragma unroll
          for (int r = 0; r < 4; ++r) {
            const float v = acc[tt][ot][r];
            dsum[ot] += fabsf(v);
            KV[tt * 16 + cg * 4 + r][col - 64] = v;
          }
      } else {                       // v: KV scatter
        #pragma unroll
        for (int tt = 0; tt < 4; ++tt)
          #pragma unroll
          for (int r = 0; r < 4; ++r)
            KV[tt * 16 + cg * 4 + r][64 + col - 128] = acc[tt][ot][r];
      }
    }
    __syncthreads();
    // fp32 outer product: kv_acc[d=ty*4+i][e=tx*4+j] += k[t,d]*v[t,e]
    for (int t = 0; t < 64; ++t) {
      float4 kk4 = *(const float4*)&KV[t][ty << 2];
      float4 vv4 = *(const float4*)&KV[t][64 + (tx << 2)];
      float kr[4] = {kk4.x, kk4.y, kk4.z, kk4.w};
      float vr[4] = {vv4.x, vv4.y, vv4.z, vv4.w};
      #pragma unroll
      for (int i = 0; i < 4; ++i)
        #pragma unroll
        for (int j = 0; j < 4; ++j)
          kv_acc[i][j] = fmaf(kr[i], vr[j], kv_acc[i][j]);
    }
  }
  // write kv partial
  float* ob = kvp + (size_t)si * (HD * HD);
  #pragma unroll
  for (int i = 0; i < 4; ++i)
    *(float4*)&ob[((ty << 2) + i) * HD + (tx << 2)] =
        make_float4(kv_acc[i][0], kv_acc[i][1], kv_acc[i][2], kv_acc[i][3]);
  // dq/dk reduction: red_q[64][4] @0, red_k[64][4] @256 (one writer per slot)
  __syncthreads();
  #pragma unroll
  for (int ot = 0; ot < 3; ++ot) {
    const int colbase = w * 48 + ot * 16;
    const int col = colbase + lr16;
    if (colbase < 64)        red[col * 4 + cg]              = dsum[ot];
    else if (colbase < 128)  red[256 + (col - 64) * 4 + cg] = dsum[ot];
  }
  __syncthreads();
  if (tid < 64) {
    dqp[(size_t)si * HD + tid] = red[tid*4] + red[tid*4+1] + red[tid*4+2] + red[tid*4+3];
  } else if (tid < 128) {
    const int d = tid - 64;
    dkp[(size_t)si * HD + d] = red[256 + d*4] + red[256 + d*4+1] + red[256 + d*4+2] + red[256 + d*4+3];
  }
}

// ---------------------------------------------------------------------------
// Reduce partials, fold both L1 denominators:
// kvs[bh][d][e] = (sum_c kvp) / (max(dq,eps)*max(dk,eps))
// ---------------------------------------------------------------------------
__global__ __launch_bounds__(256)
void kv_reduce(const float* __restrict__ kvp, const float* __restrict__ dqp,
               const float* __restrict__ dkp, float* __restrict__ kvs) {
  const int bh = blockIdx.x;
  const int tid = threadIdx.x;
  __shared__ float dqL[64], dkL[64];
  if (tid < 64) {
    float s = 0.f;
    #pragma unroll
    for (int c = 0; c < NCHUNK; ++c) s += dqp[((size_t)bh * NCHUNK + c) * HD + tid];
    dqL[tid] = fmaxf(s, EPSN);
  } else if (tid < 128) {
    const int d = tid - 64;
    float s = 0.f;
    #pragma unroll
    for (int c = 0; c < NCHUNK; ++c) s += dkp[((size_t)bh * NCHUNK + c) * HD + d];
    dkL[d] = fmaxf(s, EPSN);
  }
  __syncthreads();
  #pragma unroll
  for (int i = 0; i < 16; ++i) {
    const int idx = i * 256 + tid;    // 0..4095
    const int d = idx >> 6;
    float s = 0.f;
    #pragma unroll
    for (int c = 0; c < NCHUNK; ++c)
      s += kvp[((size_t)bh * NCHUNK + c) * (HD * HD) + idx];
    kvs[(size_t)bh * (HD * HD) + idx] = s / (dqL[d] * dkL[d]);
  }
}

// ---------------------------------------------------------------------------
// W2[b][h*64+d][c] = sum_e kvs[bh][d][e] * w_proj[c][h*64+e]
// grid (96 bh, 6 c-tiles), tile [64 d x 128 c], K=64
// ---------------------------------------------------------------------------
__global__ __launch_bounds__(256)
void w2_kernel(const float* __restrict__ kvs, const float* __restrict__ w_proj,
               float* __restrict__ W2) {
  const int bh = blockIdx.x;
  const int b = bh / HEADS, h = bh % HEADS;
  const int c0 = blockIdx.y * 128;
  const int tid = threadIdx.x;
  const int tx = tid & 15, ty = tid >> 4;
  __shared__ float KVe[64][68];   // [e][d]
  __shared__ float Wp[64][132];   // [e][c]
  #pragma unroll
  for (int i = 0; i < 4; ++i) {
    const int idx = i * 256 + tid;        // 0..1023
    const int d  = idx >> 4;              // 0..63
    const int e4 = (idx & 15) << 2;       // 0..60
    float4 v4 = *(const float4*)&kvs[(size_t)bh * (HD*HD) + (size_t)d * HD + e4];
    KVe[e4+0][d] = v4.x; KVe[e4+1][d] = v4.y;
    KVe[e4+2][d] = v4.z; KVe[e4+3][d] = v4.w;
  }
  {
    const int c = tid >> 1, half = tid & 1;
    #pragma unroll
    for (int j = 0; j < 8; ++j) {
      const int e = half * 32 + j * 4;
      float4 v4 = *(const float4*)&w_proj[(size_t)(c0 + c) * DIMC + h * HD + e];
      Wp[e+0][c] = v4.x; Wp[e+1][c] = v4.y; Wp[e+2][c] = v4.z; Wp[e+3][c] = v4.w;
    }
  }
  __syncthreads();
  float acc[4][8] = {};
  for (int e = 0; e < 64; ++e) {
    float4 a4 = *(const float4*)&KVe[e][ty << 2];
    float4 b0 = *(const float4*)&Wp[e][tx << 3];
    float4 b1 = *(const float4*)&Wp[e][(tx << 3) + 4];
    float ar[4] = {a4.x, a4.y, a4.z, a4.w};
    float br[8] = {b0.x,b0.y,b0.z,b0.w,b1.x,b1.y,b1.z,b1.w};
    #pragma unroll
    for (int i = 0; i < 4; ++i)
      #pragma unroll
      for (int j = 0; j < 8; ++j)
        acc[i][j] = fmaf(ar[i], br[j], acc[i][j]);
  }
  float* W2b = W2 + (size_t)b * DIMC * DIMC;
  #pragma unroll
  for (int i = 0; i < 4; ++i) {
    const size_t row = (size_t)(h * HD + (ty<<2) + i) * DIMC + c0 + (tx<<3);
    *(float4*)&W2b[row]     = make_float4(acc[i][0], acc[i][1], acc[i][2], acc[i][3]);
    *(float4*)&W2b[row + 4] = make_float4(acc[i][4], acc[i][5], acc[i][6], acc[i][7]);
  }
}

// ---------------------------------------------------------------------------
// W3[b][m][c] = sum_k w_qkv[k][m] * W2[b][k][c]   (TN GEMM, both k-major)
// grid (6 m-tiles, 6 c-tiles, 8 b), tile 128x128, BK=16
// ---------------------------------------------------------------------------
__global__ __launch_bounds__(256)
void w3_kernel(const float* __restrict__ w_qkv, const float* __restrict__ W2,
               float* __restrict__ W3) {
  const int m0 = blockIdx.x * 128, c0 = blockIdx.y * 128, b = blockIdx.z;
  const float* Bb = W2 + (size_t)b * DIMC * DIMC;
  const int tid = threadIdx.x;
  const int tx = tid & 15, ty = tid >> 4;
  const int skk = tid >> 4, sc8 = (tid & 15) << 3;
  __shared__ float As[16][132];
  __shared__ float Bs[16][132];
  float acc[8][8] = {};
  for (int k0 = 0; k0 < DIMC; k0 += 16) {
    __syncthreads();
    *(float4*)&As[skk][sc8]     = *(const float4*)&w_qkv[(size_t)(k0+skk) * DIMC + m0 + sc8];
    *(float4*)&As[skk][sc8 + 4] = *(const float4*)&w_qkv[(size_t)(k0+skk) * DIMC + m0 + sc8 + 4];
    *(float4*)&Bs[skk][sc8]     = *(const float4*)&Bb[(size_t)(k0+skk) * DIMC + c0 + sc8];
    *(float4*)&Bs[skk][sc8 + 4] = *(const float4*)&Bb[(size_t)(k0+skk) * DIMC + c0 + sc8 + 4];
    __syncthreads();
    #pragma unroll
    for (int kk = 0; kk < 16; ++kk) {
      float4 a0 = *(const float4*)&As[kk][ty << 2];
      float4 a1 = *(const float4*)&As[kk][64 + (ty << 2)];
      float4 b0 = *(const float4*)&Bs[kk][tx << 2];
      float4 b1 = *(const float4*)&Bs[kk][64 + (tx << 2)];
      float ar[8] = {a0.x,a0.y,a0.z,a0.w,a1.x,a1.y,a1.z,a1.w};
      float br[8] = {b0.x,b0.y,b0.z,b0.w,b1.x,b1.y,b1.z,b1.w};
      #pragma unroll
      for (int i = 0; i < 8; ++i)
        #pragma unroll
        for (int j = 0; j < 8; ++j)
          acc[i][j] = fmaf(ar[i], br[j], acc[i][j]);
    }
  }
  float* Cb = W3 + (size_t)b * DIMC * DIMC;
  #pragma unroll
  for (int i = 0; i < 8; ++i) {
    const int r = m0 + ((i < 4) ? ((ty<<2) + i) : (64 + (ty<<2) + i - 4));
    #pragma unroll
    for (int jh = 0; jh < 2; ++jh) {
      const int cb = c0 + jh*64 + (tx<<2);
      *(float4*)&Cb[(size_t)r * DIMC + cb] =
          make_float4(acc[i][jh*4+0], acc[i][jh*4+1], acc[i][jh*4+2], acc[i][jh*4+3]);
    }
  }
}

// ---------------------------------------------------------------------------
// out[b][n][c] = sum_m x[b][n][m] * W3[b][m][c] + bias[c]   (NN GEMM)
// grid (32 n-tiles, 6 c-tiles, 8 b), tile 128x128, BK=16
// ---------------------------------------------------------------------------
__global__ __launch_bounds__(256)
void final_gemm(const float* __restrict__ x, const float* __restrict__ W3,
                const float* __restrict__ bias, float* __restrict__ out) {
  const int n0 = blockIdx.x * 128, c0 = blockIdx.y * 128, b = blockIdx.z;
  const float* Ab = x + (size_t)b * SEQ * DIMC;
  const float* Bb = W3 + (size_t)b * DIMC * DIMC;
  float* Cb = out + (size_t)b * SEQ * DIMC;
  const int tid = threadIdx.x;
  const int tx = tid & 15, ty = tid >> 4;
  const int lr = tid >> 2, lc4 = (tid & 3) << 2;
  const int skk = tid >> 4, sc8 = (tid & 15) << 3;
  __shared__ float As[16][132];
  __shared__ float Bs[16][132];
  float acc[8][8] = {};
  for (int k0 = 0; k0 < DIMC; k0 += 16) {
    __syncthreads();
    #pragma unroll
    for (int half = 0; half < 2; ++half) {
      const int r = lr + half * 64;
      float4 v4 = *(const float4*)&Ab[(size_t)(n0 + r) * DIMC + k0 + lc4];
      As[lc4+0][r] = v4.x; As[lc4+1][r] = v4.y;
      As[lc4+2][r] = v4.z; As[lc4+3][r] = v4.w;
    }
    *(float4*)&Bs[skk][sc8]     = *(const float4*)&Bb[(size_t)(k0+skk) * DIMC + c0 + sc8];
    *(float4*)&Bs[skk][sc8 + 4] = *(const float4*)&Bb[(size_t)(k0+skk) * DIMC + c0 + sc8 + 4];
    __syncthreads();
    #pragma unroll
    for (int kk = 0; kk < 16; ++kk) {
      float4 a0 = *(const float4*)&As[kk][ty << 2];
      float4 a1 = *(const float4*)&As[kk][64 + (ty << 2)];
      float4 b0 = *(const float4*)&Bs[kk][tx << 2];
      float4 b1 = *(const float4*)&Bs[kk][64 + (tx << 2)];
      float ar[8] = {a0.x,a0.y,a0.z,a0.w,a1.x,a1.y,a1.z,a1.w};
      float br[8] = {b0.x,b0.y,b0.z,b0.w,b1.x,b1.y,b1.z,b1.w};
      #pragma unroll
      for (int i = 0; i < 8; ++i)
        #pragma unroll
        for (int j = 0; j < 8; ++j)
          acc[i][j] = fmaf(ar[i], br[j], acc[i][j]);
    }
  }
  #pragma unroll
  for (int i = 0; i < 8; ++i) {
    const int r = n0 + ((i < 4) ? ((ty<<2) + i) : (64 + (ty<<2) + i - 4));
    #pragma unroll
    for (int jh = 0; jh < 2; ++jh) {
      const int cb = c0 + jh*64 + (tx<<2);
      float4 bv = *(const float4*)&bias[cb];
      *(float4*)&Cb[(size_t)r * DIMC + cb] =
          make_float4(acc[i][jh*4+0] + bv.x, acc[i][jh*4+1] + bv.y,
                      acc[i][jh*4+2] + bv.z, acc[i][jh*4+3] + bv.w);
    }
  }
}

// ---------------------------------------------------------------------------
extern "C" void kernel_launch(void* const* d_in, const int* in_sizes, int n_in,
                              void* d_out, int out_size, void* d_ws, size_t ws_size,
                              hipStream_t stream) {
  const float* x      = (const float*)d_in[0];
  const float* w_qkv  = (const float*)d_in[1];
  const float* w_proj = (const float*)d_in[2];
  const float* b_proj = (const float*)d_in[3];
  float* out = (float*)d_out;
  float* ws  = (float*)d_ws;

  // workspace layout
  const size_t KVP_SZ = (size_t)BHN * NCHUNK * HD * HD;  // 3,145,728 f
  const size_t DQP_SZ = (size_t)BHN * NCHUNK * HD;       // 49,152 f
  const size_t KVS_SZ = (size_t)BHN * HD * HD;           // 393,216 f
  const size_t W_SZ   = (size_t)BATCH * DIMC * DIMC;     // 4,718,592 f
  const size_t XC_U16 = (size_t)MTOK * 1536;             // 50,331,648 u16
  const size_t WC_U16 = (size_t)THREEC * (DIMC * 2);     // 3,538,944 u16
  float* kvp = ws;
  float* dqp = kvp + KVP_SZ;
  float* dkp = dqp + DQP_SZ;
  float* kvs = dkp + DQP_SZ;
  float* W2  = kvs + KVS_SZ;
  float* W3  = W2 + W_SZ;
  u16*   xc  = (u16*)(W3 + W_SZ);
  u16*   wc  = xc + XC_U16;
  const size_t need_bytes =
      (KVP_SZ + 2*DQP_SZ + KVS_SZ + 2*W_SZ) * sizeof(float) +
      (XC_U16 + WC_U16) * sizeof(u16);
  if (ws_size < need_bytes) return;   // clean validation failure, not a fault

  const dim3 blk(256);
  // 0) split x and w_qkv into bf16 hi/lo (interleaved per 8-elem group)
  split_bf16<<<dim3(2048), blk, 0, stream>>>(x, xc, (int)(MTOK * DIMC / 8));
  split_bf16<<<dim3(864),  blk, 0, stream>>>(w_qkv, wc, (int)(THREEC * DIMC / 8));
  // 1) fused qkv GEMM (MFMA bf16x3) + |q|,|k| sums + kv outer product
  qkv_stage1<<<dim3(BHN * NCHUNK), blk, 0, stream>>>(xc, wc, kvp, dqp, dkp);
  // 2..5) unchanged fp32 pipeline
  kv_reduce<<<dim3(BHN), blk, 0, stream>>>(kvp, dqp, dkp, kvs);
  w2_kernel<<<dim3(BHN, DIMC/128), blk, 0, stream>>>(kvs, w_proj, W2);
  w3_kernel<<<dim3(DIMC/128, DIMC/128, BATCH), blk, 0, stream>>>(w_qkv, W2, W3);
  final_gemm<<<dim3(SEQ/128, DIMC/128, BATCH), blk, 0, stream>>>(x, W3, b_proj, out);
}

// Round 8
// 1523.407 us; speedup vs baseline: 3.9926x; 1.1613x over previous
//
#include <hip/hip_runtime.h>
#include <cstddef>
#include <cstdint>

#define DIMC   768
#define HEADS  12
#define HD     64
#define BATCH  8
#define SEQ    4096
#define MTOK   (BATCH*SEQ)     // 32768
#define THREEC (3*DIMC)        // 2304
#define BHN    (BATCH*HEADS)   // 96
#define NCHUNK 8               // token chunks per (b,h)
#define CHTOK  (SEQ/NCHUNK)    // 512 tokens per chunk
#define EPSN   1e-12f

typedef unsigned short u16;
typedef unsigned int   u32;
typedef __attribute__((ext_vector_type(8))) short short8;   // 8 bf16 (4 VGPR)
typedef __attribute__((ext_vector_type(4))) float f32x4;

// ---------------------------------------------------------------------------
// Split fp32 -> bf16 hi/lo pairs, interleaved per 8-element group:
// out group g (8 elems): [hi0..hi7][lo0..lo7]  (32 B per group)
// hi = RNE(bf16(x)); lo = RNE(bf16(x - hi))  -> x = hi+lo to ~2^-18 rel.
// This interleave IS the mfma_16x16x32 fragment layout: lane l of a wave
// needs 8 consecutive k of one row (row=l&15, kblk=l>>4) = one 16B piece.
// ---------------------------------------------------------------------------
__device__ inline u16 bf16_rne(float f) {
  u32 u = __float_as_uint(f);
  u32 r = u + 0x7fffu + ((u >> 16) & 1u);
  return (u16)(r >> 16);
}

__global__ __launch_bounds__(256)
void split_bf16(const float* __restrict__ in, u16* __restrict__ outp, int ngroups) {
  for (int g = blockIdx.x * 256 + threadIdx.x; g < ngroups; g += gridDim.x * 256) {
    float4 x0 = *(const float4*)(in + (size_t)g * 8);
    float4 x1 = *(const float4*)(in + (size_t)g * 8 + 4);
    float xs[8] = {x0.x, x0.y, x0.z, x0.w, x1.x, x1.y, x1.z, x1.w};
    u32 hw[4], lw[4];
    #pragma unroll
    for (int i = 0; i < 4; ++i) {
      u16 h0 = bf16_rne(xs[2*i]);
      u16 h1 = bf16_rne(xs[2*i+1]);
      float r0 = xs[2*i]   - __uint_as_float(((u32)h0) << 16);
      float r1 = xs[2*i+1] - __uint_as_float(((u32)h1) << 16);
      u16 l0 = bf16_rne(r0);
      u16 l1 = bf16_rne(r1);
      hw[i] = (u32)h0 | ((u32)h1 << 16);
      lw[i] = (u32)l0 | ((u32)l1 << 16);
    }
    uint4* dst = (uint4*)(outp + (size_t)g * 16);
    dst[0] = make_uint4(hw[0], hw[1], hw[2], hw[3]);
    dst[1] = make_uint4(lw[0], lw[1], lw[2], lw[3]);
  }
}

// ---------------------------------------------------------------------------
// Stage 1 (MFMA bf16x3, DIRECT global->register fragments): per (b,h,chunk)
// block, q,k,v for 512 tokens on the fly. A (x) and B (w_qkv) fragments are
// loaded straight from the split layout with global_load_dwordx4 — X/W never
// touch LDS, the K-loop has NO barriers. LDS holds only the fp32 KV buffer
// for the outer-product phase (33.8 KB -> 4 blocks/CU capacity, grid=3/CU).
// Per wave per K=32 step: 14 global 16B loads + 36 MFMA (hh+hl+lh per tile).
// |q|,|k| sums and kv outer product stay fp32.
// ---------------------------------------------------------------------------
__global__ __launch_bounds__(256)
void qkv_stage1(const u16* __restrict__ xc, const u16* __restrict__ wc,
                float* __restrict__ kvp, float* __restrict__ dqp,
                float* __restrict__ dkp) {
  const int bid = blockIdx.x;
  const int h = bid % HEADS;          // 12 consecutive blocks share one x-slice
  const int bc = bid / HEADS;
  const int b = bc >> 3, chunk = bc & 7;
  const int bh = b * HEADS + h;
  const int si = bh * NCHUNK + chunk; // storage index

  const int tid = threadIdx.x;
  const int w = tid >> 6, l = tid & 63;
  const int lr16 = l & 15, cg = l >> 4;
  const int tx = tid & 15, ty = tid >> 4;   // outer-product thread layout

  __shared__ __align__(16) unsigned char smem[33792];
  float (*KV)[132] = (float(*)[132])smem;   // [64][132] fp32 (outer phase)
  float* red = (float*)smem;                // 512 floats (epilogue)

  float kv_acc[4][4] = {};
  float dsum[3] = {};                 // per-ot |q| or |k| accumulation

  // B-fragment base pointers (per ot): lane reads w row (out-dim), k-block cg
  const u16* wb[3];
  #pragma unroll
  for (int ot = 0; ot < 3; ++ot) {
    const int colbase = w * 48 + ot * 16;
    const int sec = colbase >> 6;
    const int grow = sec * DIMC + h * HD + (colbase & 63) + lr16;
    wb[3-1-(2-ot)] = wc + (size_t)grow * 1536 + cg * 16;  // = wb[ot]
  }
  // A-fragment base pointers (per tt): token row tt*16+lr16, k-block cg
  const size_t tok0 = (size_t)(b * SEQ + chunk * CHTOK);

  for (int sub = 0; sub < 8; ++sub) {
    const u16* xp = xc + (tok0 + sub * 64) * 1536;
    const u16* ab[4];
    #pragma unroll
    for (int tt = 0; tt < 4; ++tt)
      ab[tt] = xp + (size_t)(tt * 16 + lr16) * 1536 + cg * 16;

    f32x4 acc[4][3];
    #pragma unroll
    for (int tt = 0; tt < 4; ++tt)
      #pragma unroll
      for (int ot = 0; ot < 3; ++ot)
        acc[tt][ot] = (f32x4){0.f, 0.f, 0.f, 0.f};

    for (int k0 = 0; k0 < DIMC; k0 += 32) {
      const int koff = k0 << 1;       // (k0/8)*16 u16
      short8 bh_[3], bl_[3];
      #pragma unroll
      for (int ot = 0; ot < 3; ++ot) {
        bh_[ot] = *(const short8*)(wb[ot] + koff);
        bl_[ot] = *(const short8*)(wb[ot] + koff + 8);
      }
      #pragma unroll
      for (int tt = 0; tt < 4; ++tt) {
        short8 ah = *(const short8*)(ab[tt] + koff);
        short8 al = *(const short8*)(ab[tt] + koff + 8);
        #pragma unroll
        for (int ot = 0; ot < 3; ++ot) {
          acc[tt][ot] = __builtin_amdgcn_mfma_f32_16x16x32_bf16(ah, bh_[ot], acc[tt][ot], 0, 0, 0);
          acc[tt][ot] = __builtin_amdgcn_mfma_f32_16x16x32_bf16(ah, bl_[ot], acc[tt][ot], 0, 0, 0);
          acc[tt][ot] = __builtin_amdgcn_mfma_f32_16x16x32_bf16(al, bh_[ot], acc[tt][ot], 0, 0, 0);
        }
      }
    }
    // C-frag (tt,ot) value r: row = tt*16 + cg*4 + r, col = w*48 + ot*16 + lr16
    __syncthreads();   // prev outer-product reads done -> KV writable
    #pragma unroll
    for (int ot = 0; ot < 3; ++ot) {
      const int colbase = w * 48 + ot * 16;
      const int col = colbase + lr16;
      if (colbase < 64) {            // q: |sum| only
        #pragma unroll
        for (int tt = 0; tt < 4; ++tt)
          #pragma unroll
          for (int r = 0; r < 4; ++r)
            dsum[ot] += fabsf(acc[tt][ot][r]);
      } else if (colbase < 128) {    // k: |sum| + KV scatter
        #pragma unroll
        for (int tt = 0; tt < 4; ++tt)
          #pragma unroll
          for (int r = 0; r < 4; ++r) {
            const float v = acc[tt][ot][r];
            dsum[ot] += fabsf(v);
            KV[tt * 16 + cg * 4 + r][col - 64] = v;
          }
      } else {                       // v: KV scatter
        #pragma unroll
        for (int tt = 0; tt < 4; ++tt)
          #pragma unroll
          for (int r = 0; r < 4; ++r)
            KV[tt * 16 + cg * 4 + r][64 + col - 128] = acc[tt][ot][r];
      }
    }
    __syncthreads();
    // fp32 outer product: kv_acc[d=ty*4+i][e=tx*4+j] += k[t,d]*v[t,e]
    for (int t = 0; t < 64; ++t) {
      float4 kk4 = *(const float4*)&KV[t][ty << 2];
      float4 vv4 = *(const float4*)&KV[t][64 + (tx << 2)];
      float kr[4] = {kk4.x, kk4.y, kk4.z, kk4.w};
      float vr[4] = {vv4.x, vv4.y, vv4.z, vv4.w};
      #pragma unroll
      for (int i = 0; i < 4; ++i)
        #pragma unroll
        for (int j = 0; j < 4; ++j)
          kv_acc[i][j] = fmaf(kr[i], vr[j], kv_acc[i][j]);
    }
  }
  // write kv partial
  float* ob = kvp + (size_t)si * (HD * HD);
  #pragma unroll
  for (int i = 0; i < 4; ++i)
    *(float4*)&ob[((ty << 2) + i) * HD + (tx << 2)] =
        make_float4(kv_acc[i][0], kv_acc[i][1], kv_acc[i][2], kv_acc[i][3]);
  // dq/dk reduction: red_q[64][4] @0, red_k[64][4] @256 (one writer per slot)
  __syncthreads();
  #pragma unroll
  for (int ot = 0; ot < 3; ++ot) {
    const int colbase = w * 48 + ot * 16;
    const int col = colbase + lr16;
    if (colbase < 64)        red[col * 4 + cg]              = dsum[ot];
    else if (colbase < 128)  red[256 + (col - 64) * 4 + cg] = dsum[ot];
  }
  __syncthreads();
  if (tid < 64) {
    dqp[(size_t)si * HD + tid] = red[tid*4] + red[tid*4+1] + red[tid*4+2] + red[tid*4+3];
  } else if (tid < 128) {
    const int d = tid - 64;
    dkp[(size_t)si * HD + d] = red[256 + d*4] + red[256 + d*4+1] + red[256 + d*4+2] + red[256 + d*4+3];
  }
}

// ---------------------------------------------------------------------------
// Reduce partials, fold both L1 denominators:
// kvs[bh][d][e] = (sum_c kvp) / (max(dq,eps)*max(dk,eps))
// ---------------------------------------------------------------------------
__global__ __launch_bounds__(256)
void kv_reduce(const float* __restrict__ kvp, const float* __restrict__ dqp,
               const float* __restrict__ dkp, float* __restrict__ kvs) {
  const int bh = blockIdx.x;
  const int tid = threadIdx.x;
  __shared__ float dqL[64], dkL[64];
  if (tid < 64) {
    float s = 0.f;
    #pragma unroll
    for (int c = 0; c < NCHUNK; ++c) s += dqp[((size_t)bh * NCHUNK + c) * HD + tid];
    dqL[tid] = fmaxf(s, EPSN);
  } else if (tid < 128) {
    const int d = tid - 64;
    float s = 0.f;
    #pragma unroll
    for (int c = 0; c < NCHUNK; ++c) s += dkp[((size_t)bh * NCHUNK + c) * HD + d];
    dkL[d] = fmaxf(s, EPSN);
  }
  __syncthreads();
  #pragma unroll
  for (int i = 0; i < 16; ++i) {
    const int idx = i * 256 + tid;    // 0..4095
    const int d = idx >> 6;
    float s = 0.f;
    #pragma unroll
    for (int c = 0; c < NCHUNK; ++c)
      s += kvp[((size_t)bh * NCHUNK + c) * (HD * HD) + idx];
    kvs[(size_t)bh * (HD * HD) + idx] = s / (dqL[d] * dkL[d]);
  }
}

// ---------------------------------------------------------------------------
// W2[b][h*64+d][c] = sum_e kvs[bh][d][e] * w_proj[c][h*64+e]
// grid (96 bh, 6 c-tiles), tile [64 d x 128 c], K=64
// ---------------------------------------------------------------------------
__global__ __launch_bounds__(256)
void w2_kernel(const float* __restrict__ kvs, const float* __restrict__ w_proj,
               float* __restrict__ W2) {
  const int bh = blockIdx.x;
  const int b = bh / HEADS, h = bh % HEADS;
  const int c0 = blockIdx.y * 128;
  const int tid = threadIdx.x;
  const int tx = tid & 15, ty = tid >> 4;
  __shared__ float KVe[64][68];   // [e][d]
  __shared__ float Wp[64][132];   // [e][c]
  #pragma unroll
  for (int i = 0; i < 4; ++i) {
    const int idx = i * 256 + tid;        // 0..1023
    const int d  = idx >> 4;              // 0..63
    const int e4 = (idx & 15) << 2;       // 0..60
    float4 v4 = *(const float4*)&kvs[(size_t)bh * (HD*HD) + (size_t)d * HD + e4];
    KVe[e4+0][d] = v4.x; KVe[e4+1][d] = v4.y;
    KVe[e4+2][d] = v4.z; KVe[e4+3][d] = v4.w;
  }
  {
    const int c = tid >> 1, half = tid & 1;
    #pragma unroll
    for (int j = 0; j < 8; ++j) {
      const int e = half * 32 + j * 4;
      float4 v4 = *(const float4*)&w_proj[(size_t)(c0 + c) * DIMC + h * HD + e];
      Wp[e+0][c] = v4.x; Wp[e+1][c] = v4.y; Wp[e+2][c] = v4.z; Wp[e+3][c] = v4.w;
    }
  }
  __syncthreads();
  float acc[4][8] = {};
  for (int e = 0; e < 64; ++e) {
    float4 a4 = *(const float4*)&KVe[e][ty << 2];
    float4 b0 = *(const float4*)&Wp[e][tx << 3];
    float4 b1 = *(const float4*)&Wp[e][(tx << 3) + 4];
    float ar[4] = {a4.x, a4.y, a4.z, a4.w};
    float br[8] = {b0.x,b0.y,b0.z,b0.w,b1.x,b1.y,b1.z,b1.w};
    #pragma unroll
    for (int i = 0; i < 4; ++i)
      #pragma unroll
      for (int j = 0; j < 8; ++j)
        acc[i][j] = fmaf(ar[i], br[j], acc[i][j]);
  }
  float* W2b = W2 + (size_t)b * DIMC * DIMC;
  #pragma unroll
  for (int i = 0; i < 4; ++i) {
    const size_t row = (size_t)(h * HD + (ty<<2) + i) * DIMC + c0 + (tx<<3);
    *(float4*)&W2b[row]     = make_float4(acc[i][0], acc[i][1], acc[i][2], acc[i][3]);
    *(float4*)&W2b[row + 4] = make_float4(acc[i][4], acc[i][5], acc[i][6], acc[i][7]);
  }
}

// ---------------------------------------------------------------------------
// W3[b][m][c] = sum_k w_qkv[k][m] * W2[b][k][c]   (TN GEMM, both k-major)
// grid (6 m-tiles, 6 c-tiles, 8 b), tile 128x128, BK=16
// ---------------------------------------------------------------------------
__global__ __launch_bounds__(256)
void w3_kernel(const float* __restrict__ w_qkv, const float* __restrict__ W2,
               float* __restrict__ W3) {
  const int m0 = blockIdx.x * 128, c0 = blockIdx.y * 128, b = blockIdx.z;
  const float* Bb = W2 + (size_t)b * DIMC * DIMC;
  const int tid = threadIdx.x;
  const int tx = tid & 15, ty = tid >> 4;
  const int skk = tid >> 4, sc8 = (tid & 15) << 3;
  __shared__ float As[16][132];
  __shared__ float Bs[16][132];
  float acc[8][8] = {};
  for (int k0 = 0; k0 < DIMC; k0 += 16) {
    __syncthreads();
    *(float4*)&As[skk][sc8]     = *(const float4*)&w_qkv[(size_t)(k0+skk) * DIMC + m0 + sc8];
    *(float4*)&As[skk][sc8 + 4] = *(const float4*)&w_qkv[(size_t)(k0+skk) * DIMC + m0 + sc8 + 4];
    *(float4*)&Bs[skk][sc8]     = *(const float4*)&Bb[(size_t)(k0+skk) * DIMC + c0 + sc8];
    *(float4*)&Bs[skk][sc8 + 4] = *(const float4*)&Bb[(size_t)(k0+skk) * DIMC + c0 + sc8 + 4];
    __syncthreads();
    #pragma unroll
    for (int kk = 0; kk < 16; ++kk) {
      float4 a0 = *(const float4*)&As[kk][ty << 2];
      float4 a1 = *(const float4*)&As[kk][64 + (ty << 2)];
      float4 b0 = *(const float4*)&Bs[kk][tx << 2];
      float4 b1 = *(const float4*)&Bs[kk][64 + (tx << 2)];
      float ar[8] = {a0.x,a0.y,a0.z,a0.w,a1.x,a1.y,a1.z,a1.w};
      float br[8] = {b0.x,b0.y,b0.z,b0.w,b1.x,b1.y,b1.z,b1.w};
      #pragma unroll
      for (int i = 0; i < 8; ++i)
        #pragma unroll
        for (int j = 0; j < 8; ++j)
          acc[i][j] = fmaf(ar[i], br[j], acc[i][j]);
    }
  }
  float* Cb = W3 + (size_t)b * DIMC * DIMC;
  #pragma unroll
  for (int i = 0; i < 8; ++i) {
    const int r = m0 + ((i < 4) ? ((ty<<2) + i) : (64 + (ty<<2) + i - 4));
    #pragma unroll
    for (int jh = 0; jh < 2; ++jh) {
      const int cb = c0 + jh*64 + (tx<<2);
      *(float4*)&Cb[(size_t)r * DIMC + cb] =
          make_float4(acc[i][jh*4+0], acc[i][jh*4+1], acc[i][jh*4+2], acc[i][jh*4+3]);
    }
  }
}

// ---------------------------------------------------------------------------
// out[b][n][c] = sum_m x[b][n][m] * W3[b][m][c] + bias[c]   (NN GEMM)
// grid (32 n-tiles, 6 c-tiles, 8 b), tile 128x128, BK=16
// ---------------------------------------------------------------------------
__global__ __launch_bounds__(256)
void final_gemm(const float* __restrict__ x, const float* __restrict__ W3,
                const float* __restrict__ bias, float* __restrict__ out) {
  const int n0 = blockIdx.x * 128, c0 = blockIdx.y * 128, b = blockIdx.z;
  const float* Ab = x + (size_t)b * SEQ * DIMC;
  const float* Bb = W3 + (size_t)b * DIMC * DIMC;
  float* Cb = out + (size_t)b * SEQ * DIMC;
  const int tid = threadIdx.x;
  const int tx = tid & 15, ty = tid >> 4;
  const int lr = tid >> 2, lc4 = (tid & 3) << 2;
  const int skk = tid >> 4, sc8 = (tid & 15) << 3;
  __shared__ float As[16][132];
  __shared__ float Bs[16][132];
  float acc[8][8] = {};
  for (int k0 = 0; k0 < DIMC; k0 += 16) {
    __syncthreads();
    #pragma unroll
    for (int half = 0; half < 2; ++half) {
      const int r = lr + half * 64;
      float4 v4 = *(const float4*)&Ab[(size_t)(n0 + r) * DIMC + k0 + lc4];
      As[lc4+0][r] = v4.x; As[lc4+1][r] = v4.y;
      As[lc4+2][r] = v4.z; As[lc4+3][r] = v4.w;
    }
    *(float4*)&Bs[skk][sc8]     = *(const float4*)&Bb[(size_t)(k0+skk) * DIMC + c0 + sc8];
    *(float4*)&Bs[skk][sc8 + 4] = *(const float4*)&Bb[(size_t)(k0+skk) * DIMC + c0 + sc8 + 4];
    __syncthreads();
    #pragma unroll
    for (int kk = 0; kk < 16; ++kk) {
      float4 a0 = *(const float4*)&As[kk][ty << 2];
      float4 a1 = *(const float4*)&As[kk][64 + (ty << 2)];
      float4 b0 = *(const float4*)&Bs[kk][tx << 2];
      float4 b1 = *(const float4*)&Bs[kk][64 + (tx << 2)];
      float ar[8] = {a0.x,a0.y,a0.z,a0.w,a1.x,a1.y,a1.z,a1.w};
      float br[8] = {b0.x,b0.y,b0.z,b0.w,b1.x,b1.y,b1.z,b1.w};
      #pragma unroll
      for (int i = 0; i < 8; ++i)
        #pragma unroll
        for (int j = 0; j < 8; ++j)
          acc[i][j] = fmaf(ar[i], br[j], acc[i][j]);
    }
  }
  #pragma unroll
  for (int i = 0; i < 8; ++i) {
    const int r = n0 + ((i < 4) ? ((ty<<2) + i) : (64 + (ty<<2) + i - 4));
    #pragma unroll
    for (int jh = 0; jh < 2; ++jh) {
      const int cb = c0 + jh*64 + (tx<<2);
      float4 bv = *(const float4*)&bias[cb];
      *(float4*)&Cb[(size_t)r * DIMC + cb] =
          make_float4(acc[i][jh*4+0] + bv.x, acc[i][jh*4+1] + bv.y,
                      acc[i][jh*4+2] + bv.z, acc[i][jh*4+3] + bv.w);
    }
  }
}

// ---------------------------------------------------------------------------
extern "C" void kernel_launch(void* const* d_in, const int* in_sizes, int n_in,
                              void* d_out, int out_size, void* d_ws, size_t ws_size,
                              hipStream_t stream) {
  const float* x      = (const float*)d_in[0];
  const float* w_qkv  = (const float*)d_in[1];
  const float* w_proj = (const float*)d_in[2];
  const float* b_proj = (const float*)d_in[3];
  float* out = (float*)d_out;
  float* ws  = (float*)d_ws;

  // workspace layout
  const size_t KVP_SZ = (size_t)BHN * NCHUNK * HD * HD;  // 3,145,728 f
  const size_t DQP_SZ = (size_t)BHN * NCHUNK * HD;       // 49,152 f
  const size_t KVS_SZ = (size_t)BHN * HD * HD;           // 393,216 f
  const size_t W_SZ   = (size_t)BATCH * DIMC * DIMC;     // 4,718,592 f
  const size_t XC_U16 = (size_t)MTOK * 1536;             // 50,331,648 u16
  const size_t WC_U16 = (size_t)THREEC * (DIMC * 2);     // 3,538,944 u16
  float* kvp = ws;
  float* dqp = kvp + KVP_SZ;
  float* dkp = dqp + DQP_SZ;
  float* kvs = dkp + DQP_SZ;
  float* W2  = kvs + KVS_SZ;
  float* W3  = W2 + W_SZ;
  u16*   xc  = (u16*)(W3 + W_SZ);
  u16*   wc  = xc + XC_U16;
  const size_t need_bytes =
      (KVP_SZ + 2*DQP_SZ + KVS_SZ + 2*W_SZ) * sizeof(float) +
      (XC_U16 + WC_U16) * sizeof(u16);
  if (ws_size < need_bytes) return;   // clean validation failure, not a fault

  const dim3 blk(256);
  // 0) split x and w_qkv into bf16 hi/lo (interleaved per 8-elem group)
  split_bf16<<<dim3(2048), blk, 0, stream>>>(x, xc, (int)(MTOK * DIMC / 8));
  split_bf16<<<dim3(864),  blk, 0, stream>>>(w_qkv, wc, (int)(THREEC * DIMC / 8));
  // 1) fused qkv GEMM (MFMA bf16x3, direct-from-global fragments)
  qkv_stage1<<<dim3(BHN * NCHUNK), blk, 0, stream>>>(xc, wc, kvp, dqp, dkp);
  // 2..5) unchanged fp32 pipeline
  kv_reduce<<<dim3(BHN), blk, 0, stream>>>(kvp, dqp, dkp, kvs);
  w2_kernel<<<dim3(BHN, DIMC/128), blk, 0, stream>>>(kvs, w_proj, W2);
  w3_kernel<<<dim3(DIMC/128, DIMC/128, BATCH), blk, 0, stream>>>(w_qkv, W2, W3);
  final_gemm<<<dim3(SEQ/128, DIMC/128, BATCH), blk, 0, stream>>>(x, W3, b_proj, out);
}

// Round 9
// 984.709 us; speedup vs baseline: 6.1768x; 1.5471x over previous
//
#include <hip/hip_runtime.h>
#include <cstddef>
#include <cstdint>

#define DIMC   768
#define HEADS  12
#define HD     64
#define BATCH  8
#define SEQ    4096
#define MTOK   (BATCH*SEQ)     // 32768
#define THREEC (3*DIMC)        // 2304
#define BHN    (BATCH*HEADS)   // 96
#define NCHUNK 8               // token chunks per (b,h)
#define CHTOK  (SEQ/NCHUNK)    // 512 tokens per chunk
#define EPSN   1e-12f
#define KT     (DIMC/32)       // 24 k-tiles
#define TILE_U16 1024          // one (16-row x 32-k) tile: hi 512 + lo 512 u16
#define ROWTILE_U16 (KT*TILE_U16)  // 24576 u16 per 16-row block

typedef unsigned short u16;
typedef unsigned int   u32;
typedef __attribute__((ext_vector_type(8))) short short8;   // 8 bf16 (4 VGPR)
typedef __attribute__((ext_vector_type(4))) float f32x4;

__device__ inline u16 bf16_rne(float f) {
  u32 u = __float_as_uint(f);
  u32 r = u + 0x7fffu + ((u >> 16) & 1u);
  return (u16)(r >> 16);
}

// ---------------------------------------------------------------------------
// Split fp32 [R][768] row-major -> bf16 hi/lo in MFMA-FRAGMENT-TILE order.
// One wave per (row-tile rt, k-tile kt): lane l handles piece
// (row = rt*16 + (l&15), k = kt*32 + (l>>4)*8 .. +8). Output tile (1024 u16):
//   [hi pieces: lane l at +l*8][lo pieces: lane l at +512+l*8]
// so a fragment load in the GEMM is lane l reading base+l*16B: COALESCED.
// ---------------------------------------------------------------------------
__global__ __launch_bounds__(256)
void split_tiles(const float* __restrict__ in, u16* __restrict__ outp,
                 int nrowtiles) {
  const int l = threadIdx.x & 63;
  const int ntiles = nrowtiles * KT;
  for (int gw = (blockIdx.x * 256 + threadIdx.x) >> 6; gw < ntiles;
       gw += (gridDim.x * 256) >> 6) {
    const int rt = gw / KT, kt = gw % KT;
    const float* src = in + (size_t)(rt * 16 + (l & 15)) * DIMC + kt * 32 + (l >> 4) * 8;
    float4 x0 = *(const float4*)src;
    float4 x1 = *(const float4*)(src + 4);
    float xs[8] = {x0.x, x0.y, x0.z, x0.w, x1.x, x1.y, x1.z, x1.w};
    u32 hw[4], lw[4];
    #pragma unroll
    for (int i = 0; i < 4; ++i) {
      u16 h0 = bf16_rne(xs[2*i]);
      u16 h1 = bf16_rne(xs[2*i+1]);
      float r0 = xs[2*i]   - __uint_as_float(((u32)h0) << 16);
      float r1 = xs[2*i+1] - __uint_as_float(((u32)h1) << 16);
      u16 l0 = bf16_rne(r0);
      u16 l1 = bf16_rne(r1);
      hw[i] = (u32)h0 | ((u32)h1 << 16);
      lw[i] = (u32)l0 | ((u32)l1 << 16);
    }
    u16* tb = outp + (size_t)gw * TILE_U16;
    *(uint4*)(tb + l * 8)       = make_uint4(hw[0], hw[1], hw[2], hw[3]);
    *(uint4*)(tb + 512 + l * 8) = make_uint4(lw[0], lw[1], lw[2], lw[3]);
  }
}

// ---------------------------------------------------------------------------
// Stage 1 (MFMA bf16x3, coalesced direct-from-global fragments).
// Identical MFMA schedule/order to R8 (bit-exact canary); only the storage
// layout of xc/wc changed -> every fragment load is 64 lanes x 16B contiguous.
// ---------------------------------------------------------------------------
__global__ __launch_bounds__(256)
void qkv_stage1(const u16* __restrict__ xc, const u16* __restrict__ wc,
                float* __restrict__ kvp, float* __restrict__ dqp,
                float* __restrict__ dkp) {
  const int bid = blockIdx.x;
  const int h = bid % HEADS;          // 12 consecutive blocks share one x-slice
  const int bc = bid / HEADS;
  const int b = bc >> 3, chunk = bc & 7;
  const int bh = b * HEADS + h;
  const int si = bh * NCHUNK + chunk; // storage index

  const int tid = threadIdx.x;
  const int w = tid >> 6, l = tid & 63;
  const int lr16 = l & 15, cg = l >> 4;
  const int tx = tid & 15, ty = tid >> 4;   // outer-product thread layout

  __shared__ __align__(16) unsigned char smem[33792];
  float (*KV)[132] = (float(*)[132])smem;   // [64][132] fp32 (outer phase)
  float* red = (float*)smem;                // 512 floats (epilogue)

  float kv_acc[4][4] = {};
  float dsum[3] = {};                 // per-ot |q| or |k| accumulation

  // B-fragment bases: out-cols colbase..+16 = w_qkv rows; tile = grow/16
  const u16* wbase[3];
  #pragma unroll
  for (int ot = 0; ot < 3; ++ot) {
    const int colbase = w * 48 + ot * 16;
    const int sec = colbase >> 6;
    const int grow = sec * DIMC + h * HD + (colbase & 63);
    wbase[ot] = wc + (size_t)(grow >> 4) * ROWTILE_U16 + (l << 3);
  }
  const int atile0 = (b * SEQ + chunk * CHTOK) >> 4;   // 16-row tile index

  for (int sub = 0; sub < 8; ++sub) {
    const u16* abase[4];
    #pragma unroll
    for (int tt = 0; tt < 4; ++tt)
      abase[tt] = xc + (size_t)(atile0 + sub * 4 + tt) * ROWTILE_U16 + (l << 3);

    f32x4 acc[4][3];
    #pragma unroll
    for (int tt = 0; tt < 4; ++tt)
      #pragma unroll
      for (int ot = 0; ot < 3; ++ot)
        acc[tt][ot] = (f32x4){0.f, 0.f, 0.f, 0.f};

    for (int kt = 0; kt < KT; ++kt) {
      const int off = kt * TILE_U16;
      short8 bh_[3], bl_[3];
      #pragma unroll
      for (int ot = 0; ot < 3; ++ot) {
        bh_[ot] = *(const short8*)(wbase[ot] + off);
        bl_[ot] = *(const short8*)(wbase[ot] + off + 512);
      }
      #pragma unroll
      for (int tt = 0; tt < 4; ++tt) {
        short8 ah = *(const short8*)(abase[tt] + off);
        short8 al = *(const short8*)(abase[tt] + off + 512);
        #pragma unroll
        for (int ot = 0; ot < 3; ++ot) {
          acc[tt][ot] = __builtin_amdgcn_mfma_f32_16x16x32_bf16(ah, bh_[ot], acc[tt][ot], 0, 0, 0);
          acc[tt][ot] = __builtin_amdgcn_mfma_f32_16x16x32_bf16(ah, bl_[ot], acc[tt][ot], 0, 0, 0);
          acc[tt][ot] = __builtin_amdgcn_mfma_f32_16x16x32_bf16(al, bh_[ot], acc[tt][ot], 0, 0, 0);
        }
      }
    }
    // C-frag (tt,ot) value r: row = tt*16 + cg*4 + r, col = w*48 + ot*16 + lr16
    __syncthreads();   // prev outer-product reads done -> KV writable
    #pragma unroll
    for (int ot = 0; ot < 3; ++ot) {
      const int colbase = w * 48 + ot * 16;
      const int col = colbase + lr16;
      if (colbase < 64) {            // q: |sum| only
        #pragma unroll
        for (int tt = 0; tt < 4; ++tt)
          #pragma unroll
          for (int r = 0; r < 4; ++r)
            dsum[ot] += fabsf(acc[tt][ot][r]);
      } else if (colbase < 128) {    // k: |sum| + KV scatter
        #pragma unroll
        for (int tt = 0; tt < 4; ++tt)
          #pragma unroll
          for (int r = 0; r < 4; ++r) {
            const float v = acc[tt][ot][r];
            dsum[ot] += fabsf(v);
            KV[tt * 16 + cg * 4 + r][col - 64] = v;
          }
      } else {                       // v: KV scatter
        #pragma unroll
        for (int tt = 0; tt < 4; ++tt)
          #pragma unroll
          for (int r = 0; r < 4; ++r)
            KV[tt * 16 + cg * 4 + r][64 + col - 128] = acc[tt][ot][r];
      }
    }
    __syncthreads();
    // fp32 outer product: kv_acc[d=ty*4+i][e=tx*4+j] += k[t,d]*v[t,e]
    for (int t = 0; t < 64; ++t) {
      float4 kk4 = *(const float4*)&KV[t][ty << 2];
      float4 vv4 = *(const float4*)&KV[t][64 + (tx << 2)];
      float kr[4] = {kk4.x, kk4.y, kk4.z, kk4.w};
      float vr[4] = {vv4.x, vv4.y, vv4.z, vv4.w};
      #pragma unroll
      for (int i = 0; i < 4; ++i)
        #pragma unroll
        for (int j = 0; j < 4; ++j)
          kv_acc[i][j] = fmaf(kr[i], vr[j], kv_acc[i][j]);
    }
  }
  // write kv partial
  float* ob = kvp + (size_t)si * (HD * HD);
  #pragma unroll
  for (int i = 0; i < 4; ++i)
    *(float4*)&ob[((ty << 2) + i) * HD + (tx << 2)] =
        make_float4(kv_acc[i][0], kv_acc[i][1], kv_acc[i][2], kv_acc[i][3]);
  // dq/dk reduction: red_q[64][4] @0, red_k[64][4] @256 (one writer per slot)
  __syncthreads();
  #pragma unroll
  for (int ot = 0; ot < 3; ++ot) {
    const int colbase = w * 48 + ot * 16;
    const int col = colbase + lr16;
    if (colbase < 64)        red[col * 4 + cg]              = dsum[ot];
    else if (colbase < 128)  red[256 + (col - 64) * 4 + cg] = dsum[ot];
  }
  __syncthreads();
  if (tid < 64) {
    dqp[(size_t)si * HD + tid] = red[tid*4] + red[tid*4+1] + red[tid*4+2] + red[tid*4+3];
  } else if (tid < 128) {
    const int d = tid - 64;
    dkp[(size_t)si * HD + d] = red[256 + d*4] + red[256 + d*4+1] + red[256 + d*4+2] + red[256 + d*4+3];
  }
}

// ---------------------------------------------------------------------------
// Reduce partials, fold both L1 denominators:
// kvs[bh][d][e] = (sum_c kvp) / (max(dq,eps)*max(dk,eps))
// ---------------------------------------------------------------------------
__global__ __launch_bounds__(256)
void kv_reduce(const float* __restrict__ kvp, const float* __restrict__ dqp,
               const float* __restrict__ dkp, float* __restrict__ kvs) {
  const int bh = blockIdx.x;
  const int tid = threadIdx.x;
  __shared__ float dqL[64], dkL[64];
  if (tid < 64) {
    float s = 0.f;
    #pragma unroll
    for (int c = 0; c < NCHUNK; ++c) s += dqp[((size_t)bh * NCHUNK + c) * HD + tid];
    dqL[tid] = fmaxf(s, EPSN);
  } else if (tid < 128) {
    const int d = tid - 64;
    float s = 0.f;
    #pragma unroll
    for (int c = 0; c < NCHUNK; ++c) s += dkp[((size_t)bh * NCHUNK + c) * HD + d];
    dkL[d] = fmaxf(s, EPSN);
  }
  __syncthreads();
  #pragma unroll
  for (int i = 0; i < 16; ++i) {
    const int idx = i * 256 + tid;    // 0..4095
    const int d = idx >> 6;
    float s = 0.f;
    #pragma unroll
    for (int c = 0; c < NCHUNK; ++c)
      s += kvp[((size_t)bh * NCHUNK + c) * (HD * HD) + idx];
    kvs[(size_t)bh * (HD * HD) + idx] = s / (dqL[d] * dkL[d]);
  }
}

// ---------------------------------------------------------------------------
// W2[b][h*64+d][c] = sum_e kvs[bh][d][e] * w_proj[c][h*64+e]
// grid (96 bh, 6 c-tiles), tile [64 d x 128 c], K=64
// ---------------------------------------------------------------------------
__global__ __launch_bounds__(256)
void w2_kernel(const float* __restrict__ kvs, const float* __restrict__ w_proj,
               float* __restrict__ W2) {
  const int bh = blockIdx.x;
  const int b = bh / HEADS, h = bh % HEADS;
  const int c0 = blockIdx.y * 128;
  const int tid = threadIdx.x;
  const int tx = tid & 15, ty = tid >> 4;
  __shared__ float KVe[64][68];   // [e][d]
  __shared__ float Wp[64][132];   // [e][c]
  #pragma unroll
  for (int i = 0; i < 4; ++i) {
    const int idx = i * 256 + tid;        // 0..1023
    const int d  = idx >> 4;              // 0..63
    const int e4 = (idx & 15) << 2;       // 0..60
    float4 v4 = *(const float4*)&kvs[(size_t)bh * (HD*HD) + (size_t)d * HD + e4];
    KVe[e4+0][d] = v4.x; KVe[e4+1][d] = v4.y;
    KVe[e4+2][d] = v4.z; KVe[e4+3][d] = v4.w;
  }
  {
    const int c = tid >> 1, half = tid & 1;
    #pragma unroll
    for (int j = 0; j < 8; ++j) {
      const int e = half * 32 + j * 4;
      float4 v4 = *(const float4*)&w_proj[(size_t)(c0 + c) * DIMC + h * HD + e];
      Wp[e+0][c] = v4.x; Wp[e+1][c] = v4.y; Wp[e+2][c] = v4.z; Wp[e+3][c] = v4.w;
    }
  }
  __syncthreads();
  float acc[4][8] = {};
  for (int e = 0; e < 64; ++e) {
    float4 a4 = *(const float4*)&KVe[e][ty << 2];
    float4 b0 = *(const float4*)&Wp[e][tx << 3];
    float4 b1 = *(const float4*)&Wp[e][(tx << 3) + 4];
    float ar[4] = {a4.x, a4.y, a4.z, a4.w};
    float br[8] = {b0.x,b0.y,b0.z,b0.w,b1.x,b1.y,b1.z,b1.w};
    #pragma unroll
    for (int i = 0; i < 4; ++i)
      #pragma unroll
      for (int j = 0; j < 8; ++j)
        acc[i][j] = fmaf(ar[i], br[j], acc[i][j]);
  }
  float* W2b = W2 + (size_t)b * DIMC * DIMC;
  #pragma unroll
  for (int i = 0; i < 4; ++i) {
    const size_t row = (size_t)(h * HD + (ty<<2) + i) * DIMC + c0 + (tx<<3);
    *(float4*)&W2b[row]     = make_float4(acc[i][0], acc[i][1], acc[i][2], acc[i][3]);
    *(float4*)&W2b[row + 4] = make_float4(acc[i][4], acc[i][5], acc[i][6], acc[i][7]);
  }
}

// ---------------------------------------------------------------------------
// W3[b][m][c] = sum_k w_qkv[k][m] * W2[b][k][c]   (TN GEMM, both k-major)
// grid (6 m-tiles, 6 c-tiles, 8 b), tile 128x128, BK=16
// ---------------------------------------------------------------------------
__global__ __launch_bounds__(256)
void w3_kernel(const float* __restrict__ w_qkv, const float* __restrict__ W2,
               float* __restrict__ W3) {
  const int m0 = blockIdx.x * 128, c0 = blockIdx.y * 128, b = blockIdx.z;
  const float* Bb = W2 + (size_t)b * DIMC * DIMC;
  const int tid = threadIdx.x;
  const int tx = tid & 15, ty = tid >> 4;
  const int skk = tid >> 4, sc8 = (tid & 15) << 3;
  __shared__ float As[16][132];
  __shared__ float Bs[16][132];
  float acc[8][8] = {};
  for (int k0 = 0; k0 < DIMC; k0 += 16) {
    __syncthreads();
    *(float4*)&As[skk][sc8]     = *(const float4*)&w_qkv[(size_t)(k0+skk) * DIMC + m0 + sc8];
    *(float4*)&As[skk][sc8 + 4] = *(const float4*)&w_qkv[(size_t)(k0+skk) * DIMC + m0 + sc8 + 4];
    *(float4*)&Bs[skk][sc8]     = *(const float4*)&Bb[(size_t)(k0+skk) * DIMC + c0 + sc8];
    *(float4*)&Bs[skk][sc8 + 4] = *(const float4*)&Bb[(size_t)(k0+skk) * DIMC + c0 + sc8 + 4];
    __syncthreads();
    #pragma unroll
    for (int kk = 0; kk < 16; ++kk) {
      float4 a0 = *(const float4*)&As[kk][ty << 2];
      float4 a1 = *(const float4*)&As[kk][64 + (ty << 2)];
      float4 b0 = *(const float4*)&Bs[kk][tx << 2];
      float4 b1 = *(const float4*)&Bs[kk][64 + (tx << 2)];
      float ar[8] = {a0.x,a0.y,a0.z,a0.w,a1.x,a1.y,a1.z,a1.w};
      float br[8] = {b0.x,b0.y,b0.z,b0.w,b1.x,b1.y,b1.z,b1.w};
      #pragma unroll
      for (int i = 0; i < 8; ++i)
        #pragma unroll
        for (int j = 0; j < 8; ++j)
          acc[i][j] = fmaf(ar[i], br[j], acc[i][j]);
    }
  }
  float* Cb = W3 + (size_t)b * DIMC * DIMC;
  #pragma unroll
  for (int i = 0; i < 8; ++i) {
    const int r = m0 + ((i < 4) ? ((ty<<2) + i) : (64 + (ty<<2) + i - 4));
    #pragma unroll
    for (int jh = 0; jh < 2; ++jh) {
      const int cb = c0 + jh*64 + (tx<<2);
      *(float4*)&Cb[(size_t)r * DIMC + cb] =
          make_float4(acc[i][jh*4+0], acc[i][jh*4+1], acc[i][jh*4+2], acc[i][jh*4+3]);
    }
  }
}

// ---------------------------------------------------------------------------
// out[b][n][c] = sum_m x[b][n][m] * W3[b][m][c] + bias[c]   (NN GEMM)
// grid (32 n-tiles, 6 c-tiles, 8 b), tile 128x128, BK=16
// ---------------------------------------------------------------------------
__global__ __launch_bounds__(256)
void final_gemm(const float* __restrict__ x, const float* __restrict__ W3,
                const float* __restrict__ bias, float* __restrict__ out) {
  const int n0 = blockIdx.x * 128, c0 = blockIdx.y * 128, b = blockIdx.z;
  const float* Ab = x + (size_t)b * SEQ * DIMC;
  const float* Bb = W3 + (size_t)b * DIMC * DIMC;
  float* Cb = out + (size_t)b * SEQ * DIMC;
  const int tid = threadIdx.x;
  const int tx = tid & 15, ty = tid >> 4;
  const int lr = tid >> 2, lc4 = (tid & 3) << 2;
  const int skk = tid >> 4, sc8 = (tid & 15) << 3;
  __shared__ float As[16][132];
  __shared__ float Bs[16][132];
  float acc[8][8] = {};
  for (int k0 = 0; k0 < DIMC; k0 += 16) {
    __syncthreads();
    #pragma unroll
    for (int half = 0; half < 2; ++half) {
      const int r = lr + half * 64;
      float4 v4 = *(const float4*)&Ab[(size_t)(n0 + r) * DIMC + k0 + lc4];
      As[lc4+0][r] = v4.x; As[lc4+1][r] = v4.y;
      As[lc4+2][r] = v4.z; As[lc4+3][r] = v4.w;
    }
    *(float4*)&Bs[skk][sc8]     = *(const float4*)&Bb[(size_t)(k0+skk) * DIMC + c0 + sc8];
    *(float4*)&Bs[skk][sc8 + 4] = *(const float4*)&Bb[(size_t)(k0+skk) * DIMC + c0 + sc8 + 4];
    __syncthreads();
    #pragma unroll
    for (int kk = 0; kk < 16; ++kk) {
      float4 a0 = *(const float4*)&As[kk][ty << 2];
      float4 a1 = *(const float4*)&As[kk][64 + (ty << 2)];
      float4 b0 = *(const float4*)&Bs[kk][tx << 2];
      float4 b1 = *(const float4*)&Bs[kk][64 + (tx << 2)];
      float ar[8] = {a0.x,a0.y,a0.z,a0.w,a1.x,a1.y,a1.z,a1.w};
      float br[8] = {b0.x,b0.y,b0.z,b0.w,b1.x,b1.y,b1.z,b1.w};
      #pragma unroll
      for (int i = 0; i < 8; ++i)
        #pragma unroll
        for (int j = 0; j < 8; ++j)
          acc[i][j] = fmaf(ar[i], br[j], acc[i][j]);
    }
  }
  #pragma unroll
  for (int i = 0; i < 8; ++i) {
    const int r = n0 + ((i < 4) ? ((ty<<2) + i) : (64 + (ty<<2) + i - 4));
    #pragma unroll
    for (int jh = 0; jh < 2; ++jh) {
      const int cb = c0 + jh*64 + (tx<<2);
      float4 bv = *(const float4*)&bias[cb];
      *(float4*)&Cb[(size_t)r * DIMC + cb] =
          make_float4(acc[i][jh*4+0] + bv.x, acc[i][jh*4+1] + bv.y,
                      acc[i][jh*4+2] + bv.z, acc[i][jh*4+3] + bv.w);
    }
  }
}

// ---------------------------------------------------------------------------
extern "C" void kernel_launch(void* const* d_in, const int* in_sizes, int n_in,
                              void* d_out, int out_size, void* d_ws, size_t ws_size,
                              hipStream_t stream) {
  const float* x      = (const float*)d_in[0];
  const float* w_qkv  = (const float*)d_in[1];
  const float* w_proj = (const float*)d_in[2];
  const float* b_proj = (const float*)d_in[3];
  float* out = (float*)d_out;
  float* ws  = (float*)d_ws;

  // workspace layout
  const size_t KVP_SZ = (size_t)BHN * NCHUNK * HD * HD;  // 3,145,728 f
  const size_t DQP_SZ = (size_t)BHN * NCHUNK * HD;       // 49,152 f
  const size_t KVS_SZ = (size_t)BHN * HD * HD;           // 393,216 f
  const size_t W_SZ   = (size_t)BATCH * DIMC * DIMC;     // 4,718,592 f
  const size_t XC_U16 = (size_t)(MTOK/16) * ROWTILE_U16; // 50,331,648 u16
  const size_t WC_U16 = (size_t)(THREEC/16) * ROWTILE_U16; // 3,538,944 u16
  float* kvp = ws;
  float* dqp = kvp + KVP_SZ;
  float* dkp = dqp + DQP_SZ;
  float* kvs = dkp + DQP_SZ;
  float* W2  = kvs + KVS_SZ;
  float* W3  = W2 + W_SZ;
  u16*   xc  = (u16*)(W3 + W_SZ);
  u16*   wc  = xc + XC_U16;
  const size_t need_bytes =
      (KVP_SZ + 2*DQP_SZ + KVS_SZ + 2*W_SZ) * sizeof(float) +
      (XC_U16 + WC_U16) * sizeof(u16);
  if (ws_size < need_bytes) return;   // clean validation failure, not a fault

  const dim3 blk(256);
  // 0) split x and w_qkv into bf16 hi/lo, fragment-tile order (wave per tile)
  split_tiles<<<dim3((MTOK/16) * KT / 4), blk, 0, stream>>>(x, xc, MTOK/16);
  split_tiles<<<dim3((THREEC/16) * KT / 4), blk, 0, stream>>>(w_qkv, wc, THREEC/16);
  // 1) fused qkv GEMM (MFMA bf16x3, coalesced direct-from-global fragments)
  qkv_stage1<<<dim3(BHN * NCHUNK), blk, 0, stream>>>(xc, wc, kvp, dqp, dkp);
  // 2..5) unchanged fp32 pipeline
  kv_reduce<<<dim3(BHN), blk, 0, stream>>>(kvp, dqp, dkp, kvs);
  w2_kernel<<<dim3(BHN, DIMC/128), blk, 0, stream>>>(kvs, w_proj, W2);
  w3_kernel<<<dim3(DIMC/128, DIMC/128, BATCH), blk, 0, stream>>>(w_qkv, W2, W3);
  final_gemm<<<dim3(SEQ/128, DIMC/128, BATCH), blk, 0, stream>>>(x, W3, b_proj, out);
}

// Round 10
// 683.516 us; speedup vs baseline: 8.8987x; 1.4407x over previous
//
#include <hip/hip_runtime.h>
#include <cstddef>
#include <cstdint>

#define DIMC   768
#define HEADS  12
#define HD     64
#define BATCH  8
#define SEQ    4096
#define MTOK   (BATCH*SEQ)     // 32768
#define THREEC (3*DIMC)        // 2304
#define BHN    (BATCH*HEADS)   // 96
#define NCHUNK 8               // token chunks per (b,h)
#define CHTOK  (SEQ/NCHUNK)    // 512 tokens per chunk
#define EPSN   1e-12f
#define KT     (DIMC/32)       // 24 k-tiles
#define TILE_U16 1024          // one (16-row x 32-k) tile: hi 512 + lo 512 u16
#define ROWTILE_U16 (KT*TILE_U16)  // 24576 u16 per 16-row block

typedef unsigned short u16;
typedef unsigned int   u32;
typedef __attribute__((ext_vector_type(8))) short short8;   // 8 bf16 (4 VGPR)
typedef __attribute__((ext_vector_type(4))) float f32x4;

__device__ inline u16 bf16_rne(float f) {
  u32 u = __float_as_uint(f);
  u32 r = u + 0x7fffu + ((u >> 16) & 1u);
  return (u16)(r >> 16);
}

// ---------------------------------------------------------------------------
// Split fp32 [R][768] row-major -> bf16 hi/lo in MFMA-FRAGMENT-TILE order.
// One wave per (row-tile rt, k-tile kt): lane l handles piece
// (row = rt*16 + (l&15), k = kt*32 + (l>>4)*8 .. +8). Output tile (1024 u16):
//   [hi pieces: lane l at +l*8][lo pieces: lane l at +512+l*8]
// so a fragment load in the GEMM is lane l reading base+l*16B: COALESCED.
// ---------------------------------------------------------------------------
__global__ __launch_bounds__(256)
void split_tiles(const float* __restrict__ in, u16* __restrict__ outp,
                 int nrowtiles) {
  const int l = threadIdx.x & 63;
  const int ntiles = nrowtiles * KT;
  for (int gw = (blockIdx.x * 256 + threadIdx.x) >> 6; gw < ntiles;
       gw += (gridDim.x * 256) >> 6) {
    const int rt = gw / KT, kt = gw % KT;
    const float* src = in + (size_t)(rt * 16 + (l & 15)) * DIMC + kt * 32 + (l >> 4) * 8;
    float4 x0 = *(const float4*)src;
    float4 x1 = *(const float4*)(src + 4);
    float xs[8] = {x0.x, x0.y, x0.z, x0.w, x1.x, x1.y, x1.z, x1.w};
    u32 hw[4], lw[4];
    #pragma unroll
    for (int i = 0; i < 4; ++i) {
      u16 h0 = bf16_rne(xs[2*i]);
      u16 h1 = bf16_rne(xs[2*i+1]);
      float r0 = xs[2*i]   - __uint_as_float(((u32)h0) << 16);
      float r1 = xs[2*i+1] - __uint_as_float(((u32)h1) << 16);
      u16 l0 = bf16_rne(r0);
      u16 l1 = bf16_rne(r1);
      hw[i] = (u32)h0 | ((u32)h1 << 16);
      lw[i] = (u32)l0 | ((u32)l1 << 16);
    }
    u16* tb = outp + (size_t)gw * TILE_U16;
    *(uint4*)(tb + l * 8)       = make_uint4(hw[0], hw[1], hw[2], hw[3]);
    *(uint4*)(tb + 512 + l * 8) = make_uint4(lw[0], lw[1], lw[2], lw[3]);
  }
}

// ---------------------------------------------------------------------------
// Stage 1 (MFMA bf16x3, coalesced direct-from-global fragments). Unchanged
// from R9 (bit-exact verified).
// ---------------------------------------------------------------------------
__global__ __launch_bounds__(256)
void qkv_stage1(const u16* __restrict__ xc, const u16* __restrict__ wc,
                float* __restrict__ kvp, float* __restrict__ dqp,
                float* __restrict__ dkp) {
  const int bid = blockIdx.x;
  const int h = bid % HEADS;
  const int bc = bid / HEADS;
  const int b = bc >> 3, chunk = bc & 7;
  const int bh = b * HEADS + h;
  const int si = bh * NCHUNK + chunk;

  const int tid = threadIdx.x;
  const int w = tid >> 6, l = tid & 63;
  const int lr16 = l & 15, cg = l >> 4;
  const int tx = tid & 15, ty = tid >> 4;

  __shared__ __align__(16) unsigned char smem[33792];
  float (*KV)[132] = (float(*)[132])smem;
  float* red = (float*)smem;

  float kv_acc[4][4] = {};
  float dsum[3] = {};

  const u16* wbase[3];
  #pragma unroll
  for (int ot = 0; ot < 3; ++ot) {
    const int colbase = w * 48 + ot * 16;
    const int sec = colbase >> 6;
    const int grow = sec * DIMC + h * HD + (colbase & 63);
    wbase[ot] = wc + (size_t)(grow >> 4) * ROWTILE_U16 + (l << 3);
  }
  const int atile0 = (b * SEQ + chunk * CHTOK) >> 4;

  for (int sub = 0; sub < 8; ++sub) {
    const u16* abase[4];
    #pragma unroll
    for (int tt = 0; tt < 4; ++tt)
      abase[tt] = xc + (size_t)(atile0 + sub * 4 + tt) * ROWTILE_U16 + (l << 3);

    f32x4 acc[4][3];
    #pragma unroll
    for (int tt = 0; tt < 4; ++tt)
      #pragma unroll
      for (int ot = 0; ot < 3; ++ot)
        acc[tt][ot] = (f32x4){0.f, 0.f, 0.f, 0.f};

    for (int kt = 0; kt < KT; ++kt) {
      const int off = kt * TILE_U16;
      short8 bh_[3], bl_[3];
      #pragma unroll
      for (int ot = 0; ot < 3; ++ot) {
        bh_[ot] = *(const short8*)(wbase[ot] + off);
        bl_[ot] = *(const short8*)(wbase[ot] + off + 512);
      }
      #pragma unroll
      for (int tt = 0; tt < 4; ++tt) {
        short8 ah = *(const short8*)(abase[tt] + off);
        short8 al = *(const short8*)(abase[tt] + off + 512);
        #pragma unroll
        for (int ot = 0; ot < 3; ++ot) {
          acc[tt][ot] = __builtin_amdgcn_mfma_f32_16x16x32_bf16(ah, bh_[ot], acc[tt][ot], 0, 0, 0);
          acc[tt][ot] = __builtin_amdgcn_mfma_f32_16x16x32_bf16(ah, bl_[ot], acc[tt][ot], 0, 0, 0);
          acc[tt][ot] = __builtin_amdgcn_mfma_f32_16x16x32_bf16(al, bh_[ot], acc[tt][ot], 0, 0, 0);
        }
      }
    }
    __syncthreads();
    #pragma unroll
    for (int ot = 0; ot < 3; ++ot) {
      const int colbase = w * 48 + ot * 16;
      const int col = colbase + lr16;
      if (colbase < 64) {
        #pragma unroll
        for (int tt = 0; tt < 4; ++tt)
          #pragma unroll
          for (int r = 0; r < 4; ++r)
            dsum[ot] += fabsf(acc[tt][ot][r]);
      } else if (colbase < 128) {
        #pragma unroll
        for (int tt = 0; tt < 4; ++tt)
          #pragma unroll
          for (int r = 0; r < 4; ++r) {
            const float v = acc[tt][ot][r];
            dsum[ot] += fabsf(v);
            KV[tt * 16 + cg * 4 + r][col - 64] = v;
          }
      } else {
        #pragma unroll
        for (int tt = 0; tt < 4; ++tt)
          #pragma unroll
          for (int r = 0; r < 4; ++r)
            KV[tt * 16 + cg * 4 + r][64 + col - 128] = acc[tt][ot][r];
      }
    }
    __syncthreads();
    for (int t = 0; t < 64; ++t) {
      float4 kk4 = *(const float4*)&KV[t][ty << 2];
      float4 vv4 = *(const float4*)&KV[t][64 + (tx << 2)];
      float kr[4] = {kk4.x, kk4.y, kk4.z, kk4.w};
      float vr[4] = {vv4.x, vv4.y, vv4.z, vv4.w};
      #pragma unroll
      for (int i = 0; i < 4; ++i)
        #pragma unroll
        for (int j = 0; j < 4; ++j)
          kv_acc[i][j] = fmaf(kr[i], vr[j], kv_acc[i][j]);
    }
  }
  float* ob = kvp + (size_t)si * (HD * HD);
  #pragma unroll
  for (int i = 0; i < 4; ++i)
    *(float4*)&ob[((ty << 2) + i) * HD + (tx << 2)] =
        make_float4(kv_acc[i][0], kv_acc[i][1], kv_acc[i][2], kv_acc[i][3]);
  __syncthreads();
  #pragma unroll
  for (int ot = 0; ot < 3; ++ot) {
    const int colbase = w * 48 + ot * 16;
    const int col = colbase + lr16;
    if (colbase < 64)        red[col * 4 + cg]              = dsum[ot];
    else if (colbase < 128)  red[256 + (col - 64) * 4 + cg] = dsum[ot];
  }
  __syncthreads();
  if (tid < 64) {
    dqp[(size_t)si * HD + tid] = red[tid*4] + red[tid*4+1] + red[tid*4+2] + red[tid*4+3];
  } else if (tid < 128) {
    const int d = tid - 64;
    dkp[(size_t)si * HD + d] = red[256 + d*4] + red[256 + d*4+1] + red[256 + d*4+2] + red[256 + d*4+3];
  }
}

// ---------------------------------------------------------------------------
__global__ __launch_bounds__(256)
void kv_reduce(const float* __restrict__ kvp, const float* __restrict__ dqp,
               const float* __restrict__ dkp, float* __restrict__ kvs) {
  const int bh = blockIdx.x;
  const int tid = threadIdx.x;
  __shared__ float dqL[64], dkL[64];
  if (tid < 64) {
    float s = 0.f;
    #pragma unroll
    for (int c = 0; c < NCHUNK; ++c) s += dqp[((size_t)bh * NCHUNK + c) * HD + tid];
    dqL[tid] = fmaxf(s, EPSN);
  } else if (tid < 128) {
    const int d = tid - 64;
    float s = 0.f;
    #pragma unroll
    for (int c = 0; c < NCHUNK; ++c) s += dkp[((size_t)bh * NCHUNK + c) * HD + d];
    dkL[d] = fmaxf(s, EPSN);
  }
  __syncthreads();
  #pragma unroll
  for (int i = 0; i < 16; ++i) {
    const int idx = i * 256 + tid;
    const int d = idx >> 6;
    float s = 0.f;
    #pragma unroll
    for (int c = 0; c < NCHUNK; ++c)
      s += kvp[((size_t)bh * NCHUNK + c) * (HD * HD) + idx];
    kvs[(size_t)bh * (HD * HD) + idx] = s / (dqL[d] * dkL[d]);
  }
}

// ---------------------------------------------------------------------------
__global__ __launch_bounds__(256)
void w2_kernel(const float* __restrict__ kvs, const float* __restrict__ w_proj,
               float* __restrict__ W2) {
  const int bh = blockIdx.x;
  const int b = bh / HEADS, h = bh % HEADS;
  const int c0 = blockIdx.y * 128;
  const int tid = threadIdx.x;
  const int tx = tid & 15, ty = tid >> 4;
  __shared__ float KVe[64][68];
  __shared__ float Wp[64][132];
  #pragma unroll
  for (int i = 0; i < 4; ++i) {
    const int idx = i * 256 + tid;
    const int d  = idx >> 4;
    const int e4 = (idx & 15) << 2;
    float4 v4 = *(const float4*)&kvs[(size_t)bh * (HD*HD) + (size_t)d * HD + e4];
    KVe[e4+0][d] = v4.x; KVe[e4+1][d] = v4.y;
    KVe[e4+2][d] = v4.z; KVe[e4+3][d] = v4.w;
  }
  {
    const int c = tid >> 1, half = tid & 1;
    #pragma unroll
    for (int j = 0; j < 8; ++j) {
      const int e = half * 32 + j * 4;
      float4 v4 = *(const float4*)&w_proj[(size_t)(c0 + c) * DIMC + h * HD + e];
      Wp[e+0][c] = v4.x; Wp[e+1][c] = v4.y; Wp[e+2][c] = v4.z; Wp[e+3][c] = v4.w;
    }
  }
  __syncthreads();
  float acc[4][8] = {};
  for (int e = 0; e < 64; ++e) {
    float4 a4 = *(const float4*)&KVe[e][ty << 2];
    float4 b0 = *(const float4*)&Wp[e][tx << 3];
    float4 b1 = *(const float4*)&Wp[e][(tx << 3) + 4];
    float ar[4] = {a4.x, a4.y, a4.z, a4.w};
    float br[8] = {b0.x,b0.y,b0.z,b0.w,b1.x,b1.y,b1.z,b1.w};
    #pragma unroll
    for (int i = 0; i < 4; ++i)
      #pragma unroll
      for (int j = 0; j < 8; ++j)
        acc[i][j] = fmaf(ar[i], br[j], acc[i][j]);
  }
  float* W2b = W2 + (size_t)b * DIMC * DIMC;
  #pragma unroll
  for (int i = 0; i < 4; ++i) {
    const size_t row = (size_t)(h * HD + (ty<<2) + i) * DIMC + c0 + (tx<<3);
    *(float4*)&W2b[row]     = make_float4(acc[i][0], acc[i][1], acc[i][2], acc[i][3]);
    *(float4*)&W2b[row + 4] = make_float4(acc[i][4], acc[i][5], acc[i][6], acc[i][7]);
  }
}

// ---------------------------------------------------------------------------
// W3T[b][c][m] = sum_k W2[b][k][c] * w_qkv[k][m]  (TN GEMM, transposed store;
// values bit-identical to the old W3[m][c], just laid out [c][m] so the final
// MFMA GEMM can fragment-load B by column c with k contiguous)
// grid (6 c-tiles, 6 m-tiles, 8 b), tile 128x128, BK=16
// ---------------------------------------------------------------------------
__global__ __launch_bounds__(256)
void w3t_kernel(const float* __restrict__ w_qkv, const float* __restrict__ W2,
                float* __restrict__ W3T) {
  const int c0 = blockIdx.x * 128, m0 = blockIdx.y * 128, b = blockIdx.z;
  const float* Ab = W2 + (size_t)b * DIMC * DIMC;   // A[k][c]
  const int tid = threadIdx.x;
  const int tx = tid & 15, ty = tid >> 4;
  const int skk = tid >> 4, sc8 = (tid & 15) << 3;
  __shared__ float As[16][132];
  __shared__ float Bs[16][132];
  float acc[8][8] = {};
  for (int k0 = 0; k0 < DIMC; k0 += 16) {
    __syncthreads();
    *(float4*)&As[skk][sc8]     = *(const float4*)&Ab[(size_t)(k0+skk) * DIMC + c0 + sc8];
    *(float4*)&As[skk][sc8 + 4] = *(const float4*)&Ab[(size_t)(k0+skk) * DIMC + c0 + sc8 + 4];
    *(float4*)&Bs[skk][sc8]     = *(const float4*)&w_qkv[(size_t)(k0+skk) * DIMC + m0 + sc8];
    *(float4*)&Bs[skk][sc8 + 4] = *(const float4*)&w_qkv[(size_t)(k0+skk) * DIMC + m0 + sc8 + 4];
    __syncthreads();
    #pragma unroll
    for (int kk = 0; kk < 16; ++kk) {
      float4 a0 = *(const float4*)&As[kk][ty << 2];
      float4 a1 = *(const float4*)&As[kk][64 + (ty << 2)];
      float4 b0 = *(const float4*)&Bs[kk][tx << 2];
      float4 b1 = *(const float4*)&Bs[kk][64 + (tx << 2)];
      float ar[8] = {a0.x,a0.y,a0.z,a0.w,a1.x,a1.y,a1.z,a1.w};
      float br[8] = {b0.x,b0.y,b0.z,b0.w,b1.x,b1.y,b1.z,b1.w};
      #pragma unroll
      for (int i = 0; i < 8; ++i)
        #pragma unroll
        for (int j = 0; j < 8; ++j)
          acc[i][j] = fmaf(ar[i], br[j], acc[i][j]);
    }
  }
  float* Cb = W3T + (size_t)b * DIMC * DIMC;
  #pragma unroll
  for (int i = 0; i < 8; ++i) {
    const int r = c0 + ((i < 4) ? ((ty<<2) + i) : (64 + (ty<<2) + i - 4));
    #pragma unroll
    for (int jh = 0; jh < 2; ++jh) {
      const int cb = m0 + jh*64 + (tx<<2);
      *(float4*)&Cb[(size_t)r * DIMC + cb] =
          make_float4(acc[i][jh*4+0], acc[i][jh*4+1], acc[i][jh*4+2], acc[i][jh*4+3]);
    }
  }
}

// ---------------------------------------------------------------------------
// out[b][n][c] = sum_m x[b][n][m] * W3T[b][c][m] + bias[c]
// MFMA bf16x3, coalesced direct-from-global fragments (A from xc — shared
// with stage1! — B from w3c). 64 tokens x 192 cols per block, no LDS.
// grid (MTOK/64 = 512, 768/192 = 4)
// ---------------------------------------------------------------------------
__global__ __launch_bounds__(256)
void final_gemm_mfma(const u16* __restrict__ xc, const u16* __restrict__ w3c,
                     const float* __restrict__ bias, float* __restrict__ out) {
  const int tid = threadIdx.x;
  const int w = tid >> 6, l = tid & 63;
  const int lr16 = l & 15, cg = l >> 4;
  const int ntile = blockIdx.x;          // 64-token block
  const int c0 = blockIdx.y * 192;
  const int b = ntile >> 6;              // SEQ/64 = 64 n-tiles per batch
  const int colbase0 = c0 + w * 48;

  const u16* wbase[3];
  #pragma unroll
  for (int ot = 0; ot < 3; ++ot) {
    const int c = colbase0 + ot * 16;
    wbase[ot] = w3c + (size_t)(b * (DIMC/16) + (c >> 4)) * ROWTILE_U16 + (l << 3);
  }
  const u16* abase[4];
  #pragma unroll
  for (int tt = 0; tt < 4; ++tt)
    abase[tt] = xc + (size_t)(ntile * 4 + tt) * ROWTILE_U16 + (l << 3);

  f32x4 acc[4][3];
  #pragma unroll
  for (int tt = 0; tt < 4; ++tt)
    #pragma unroll
    for (int ot = 0; ot < 3; ++ot)
      acc[tt][ot] = (f32x4){0.f, 0.f, 0.f, 0.f};

  for (int kt = 0; kt < KT; ++kt) {
    const int off = kt * TILE_U16;
    short8 bh_[3], bl_[3];
    #pragma unroll
    for (int ot = 0; ot < 3; ++ot) {
      bh_[ot] = *(const short8*)(wbase[ot] + off);
      bl_[ot] = *(const short8*)(wbase[ot] + off + 512);
    }
    #pragma unroll
    for (int tt = 0; tt < 4; ++tt) {
      short8 ah = *(const short8*)(abase[tt] + off);
      short8 al = *(const short8*)(abase[tt] + off + 512);
      #pragma unroll
      for (int ot = 0; ot < 3; ++ot) {
        acc[tt][ot] = __builtin_amdgcn_mfma_f32_16x16x32_bf16(ah, bh_[ot], acc[tt][ot], 0, 0, 0);
        acc[tt][ot] = __builtin_amdgcn_mfma_f32_16x16x32_bf16(ah, bl_[ot], acc[tt][ot], 0, 0, 0);
        acc[tt][ot] = __builtin_amdgcn_mfma_f32_16x16x32_bf16(al, bh_[ot], acc[tt][ot], 0, 0, 0);
      }
    }
  }
  // epilogue: C-frag (tt,ot)[r] -> row = ntile*64 + tt*16 + cg*4 + r,
  //                                col = colbase0 + ot*16 + lr16
  #pragma unroll
  for (int ot = 0; ot < 3; ++ot) {
    const int col = colbase0 + ot * 16 + lr16;
    const float bv = bias[col];
    #pragma unroll
    for (int tt = 0; tt < 4; ++tt) {
      const size_t row0 = (size_t)ntile * 64 + tt * 16 + cg * 4;
      #pragma unroll
      for (int r = 0; r < 4; ++r)
        out[(row0 + r) * DIMC + col] = acc[tt][ot][r] + bv;
    }
  }
}

// ---------------------------------------------------------------------------
extern "C" void kernel_launch(void* const* d_in, const int* in_sizes, int n_in,
                              void* d_out, int out_size, void* d_ws, size_t ws_size,
                              hipStream_t stream) {
  const float* x      = (const float*)d_in[0];
  const float* w_qkv  = (const float*)d_in[1];
  const float* w_proj = (const float*)d_in[2];
  const float* b_proj = (const float*)d_in[3];
  float* out = (float*)d_out;
  float* ws  = (float*)d_ws;

  // workspace layout
  const size_t KVP_SZ = (size_t)BHN * NCHUNK * HD * HD;    // f32
  const size_t DQP_SZ = (size_t)BHN * NCHUNK * HD;         // f32
  const size_t KVS_SZ = (size_t)BHN * HD * HD;             // f32
  const size_t W_SZ   = (size_t)BATCH * DIMC * DIMC;       // f32
  const size_t XC_U16  = (size_t)(MTOK/16) * ROWTILE_U16;    // 50,331,648
  const size_t WC_U16  = (size_t)(THREEC/16) * ROWTILE_U16;  //  3,538,944
  const size_t W3C_U16 = (size_t)(BATCH*DIMC/16) * ROWTILE_U16; // 9,437,184
  float* kvp = ws;
  float* dqp = kvp + KVP_SZ;
  float* dkp = dqp + DQP_SZ;
  float* kvs = dkp + DQP_SZ;
  float* W2  = kvs + KVS_SZ;
  float* W3T = W2 + W_SZ;
  u16*   xc  = (u16*)(W3T + W_SZ);
  u16*   wc  = xc + XC_U16;
  u16*   w3c = wc + WC_U16;
  const size_t need_bytes =
      (KVP_SZ + 2*DQP_SZ + KVS_SZ + 2*W_SZ) * sizeof(float) +
      (XC_U16 + WC_U16 + W3C_U16) * sizeof(u16);
  if (ws_size < need_bytes) return;   // clean validation failure, not a fault

  const dim3 blk(256);
  // 0) split x and w_qkv into bf16 hi/lo, fragment-tile order
  split_tiles<<<dim3((MTOK/16) * KT / 4), blk, 0, stream>>>(x, xc, MTOK/16);
  split_tiles<<<dim3((THREEC/16) * KT / 4), blk, 0, stream>>>(w_qkv, wc, THREEC/16);
  // 1) fused qkv GEMM (MFMA bf16x3) + |q|,|k| sums + kv outer product
  qkv_stage1<<<dim3(BHN * NCHUNK), blk, 0, stream>>>(xc, wc, kvp, dqp, dkp);
  // 2) reduce partials + fold denominators
  kv_reduce<<<dim3(BHN), blk, 0, stream>>>(kvp, dqp, dkp, kvs);
  // 3) W2 = kvs @ w_proj^T (per head-row block)
  w2_kernel<<<dim3(BHN, DIMC/128), blk, 0, stream>>>(kvs, w_proj, W2);
  // 4) W3T[b][c][m] (transposed store for fragment loading)
  w3t_kernel<<<dim3(DIMC/128, DIMC/128, BATCH), blk, 0, stream>>>(w_qkv, W2, W3T);
  // 5) split W3T into fragment tiles
  split_tiles<<<dim3((BATCH*DIMC/16) * KT / 4), blk, 0, stream>>>(W3T, w3c, BATCH*DIMC/16);
  // 6) out = x @ W3^T + bias  (MFMA bf16x3, A-tiles shared with stage1)
  final_gemm_mfma<<<dim3(MTOK/64, DIMC/192), blk, 0, stream>>>(xc, w3c, b_proj, out);
}

// Round 11
// 576.311 us; speedup vs baseline: 10.5540x; 1.1860x over previous
//
#include <hip/hip_runtime.h>
#include <cstddef>
#include <cstdint>

#define DIMC   768
#define HEADS  12
#define HD     64
#define BATCH  8
#define SEQ    4096
#define MTOK   (BATCH*SEQ)     // 32768
#define THREEC (3*DIMC)        // 2304
#define BHN    (BATCH*HEADS)   // 96
#define NCHUNK 8               // token chunks per (b,h)
#define CHTOK  (SEQ/NCHUNK)    // 512 tokens per chunk
#define EPSN   1e-12f
#define KT     (DIMC/32)       // 24 k-tiles
#define TILE_U16 1024          // one (16-row x 32-k) tile: hi 512 + lo 512 u16
#define ROWTILE_U16 (KT*TILE_U16)  // 24576 u16 per 16-row block

typedef unsigned short u16;
typedef unsigned int   u32;
typedef __attribute__((ext_vector_type(8))) short short8;   // 8 bf16 (4 VGPR)
typedef __attribute__((ext_vector_type(4))) float f32x4;

__device__ inline u16 bf16_rne(float f) {
  u32 u = __float_as_uint(f);
  u32 r = u + 0x7fffu + ((u >> 16) & 1u);
  return (u16)(r >> 16);
}

// ---------------------------------------------------------------------------
// Split fp32 [R][768] row-major -> bf16 hi/lo in MFMA-FRAGMENT-TILE order.
// Tile (16 rows x 32 k): lane l piece (row=l&15, k=(l>>4)*8..+8) at +l*8 (hi),
// +512+l*8 (lo) -> fragment loads are 64 lanes x contiguous 16B: COALESCED.
// ---------------------------------------------------------------------------
__global__ __launch_bounds__(256)
void split_tiles(const float* __restrict__ in, u16* __restrict__ outp,
                 int nrowtiles) {
  const int l = threadIdx.x & 63;
  const int ntiles = nrowtiles * KT;
  for (int gw = (blockIdx.x * 256 + threadIdx.x) >> 6; gw < ntiles;
       gw += (gridDim.x * 256) >> 6) {
    const int rt = gw / KT, kt = gw % KT;
    const float* src = in + (size_t)(rt * 16 + (l & 15)) * DIMC + kt * 32 + (l >> 4) * 8;
    float4 x0 = *(const float4*)src;
    float4 x1 = *(const float4*)(src + 4);
    float xs[8] = {x0.x, x0.y, x0.z, x0.w, x1.x, x1.y, x1.z, x1.w};
    u32 hw[4], lw[4];
    #pragma unroll
    for (int i = 0; i < 4; ++i) {
      u16 h0 = bf16_rne(xs[2*i]);
      u16 h1 = bf16_rne(xs[2*i+1]);
      float r0 = xs[2*i]   - __uint_as_float(((u32)h0) << 16);
      float r1 = xs[2*i+1] - __uint_as_float(((u32)h1) << 16);
      u16 l0 = bf16_rne(r0);
      u16 l1 = bf16_rne(r1);
      hw[i] = (u32)h0 | ((u32)h1 << 16);
      lw[i] = (u32)l0 | ((u32)l1 << 16);
    }
    u16* tb = outp + (size_t)gw * TILE_U16;
    *(uint4*)(tb + l * 8)       = make_uint4(hw[0], hw[1], hw[2], hw[3]);
    *(uint4*)(tb + 512 + l * 8) = make_uint4(lw[0], lw[1], lw[2], lw[3]);
  }
}

// ---------------------------------------------------------------------------
// Transposed split: source element (row rr, k kk) = in[kk*ld + rr].
// Used for w_qkv q-section^T (rows m = input dim, k = q-output dim).
// ---------------------------------------------------------------------------
__global__ __launch_bounds__(256)
void split_tiles_t(const float* __restrict__ in, u16* __restrict__ outp,
                   int nrowtiles, int ld) {
  const int l = threadIdx.x & 63;
  const int ntiles = nrowtiles * KT;
  for (int gw = (blockIdx.x * 256 + threadIdx.x) >> 6; gw < ntiles;
       gw += (gridDim.x * 256) >> 6) {
    const int rt = gw / KT, kt = gw % KT;
    const int m = rt * 16 + (l & 15);
    const int k0 = kt * 32 + (l >> 4) * 8;
    float xs[8];
    #pragma unroll
    for (int j = 0; j < 8; ++j) xs[j] = in[(size_t)(k0 + j) * ld + m];
    u32 hw[4], lw[4];
    #pragma unroll
    for (int i = 0; i < 4; ++i) {
      u16 h0 = bf16_rne(xs[2*i]);
      u16 h1 = bf16_rne(xs[2*i+1]);
      float r0 = xs[2*i]   - __uint_as_float(((u32)h0) << 16);
      float r1 = xs[2*i+1] - __uint_as_float(((u32)h1) << 16);
      u16 l0 = bf16_rne(r0);
      u16 l1 = bf16_rne(r1);
      hw[i] = (u32)h0 | ((u32)h1 << 16);
      lw[i] = (u32)l0 | ((u32)l1 << 16);
    }
    u16* tb = outp + (size_t)gw * TILE_U16;
    *(uint4*)(tb + l * 8)       = make_uint4(hw[0], hw[1], hw[2], hw[3]);
    *(uint4*)(tb + 512 + l * 8) = make_uint4(lw[0], lw[1], lw[2], lw[3]);
  }
}

// ---------------------------------------------------------------------------
// Stage 1: main qkv GEMM (MFMA bf16x3, coalesced global fragments — R9) and
// NOW the kv outer product on MFMA too: k,v accs are scattered to LDS as
// bf16 hi/lo fragment tiles (k^T: 16KB, v: 16KB), then kv += k^T·v via
// 24 MFMA/sub/wave (vs 16k VALU cycles before).
// ---------------------------------------------------------------------------
__global__ __launch_bounds__(256)
void qkv_stage1(const u16* __restrict__ xc, const u16* __restrict__ wc,
                float* __restrict__ kvp, float* __restrict__ dqp,
                float* __restrict__ dkp) {
  const int bid = blockIdx.x;
  const int h = bid % HEADS;
  const int bc = bid / HEADS;
  const int b = bc >> 3, chunk = bc & 7;
  const int bh = b * HEADS + h;
  const int si = bh * NCHUNK + chunk;

  const int tid = threadIdx.x;
  const int w = tid >> 6, l = tid & 63;
  const int lr16 = l & 15, cg = l >> 4;

  __shared__ __align__(16) unsigned char smem[33792];
  u16* lds16 = (u16*)smem;        // A(k^T) tiles [0,8192) u16, B(v) [8192,16384)
  float* red = (float*)smem;      // epilogue scratch

  f32x4 kvacc[4] = {(f32x4){0,0,0,0},(f32x4){0,0,0,0},(f32x4){0,0,0,0},(f32x4){0,0,0,0}};
  float dsum[3] = {};

  const u16* wbase[3];
  #pragma unroll
  for (int ot = 0; ot < 3; ++ot) {
    const int colbase = w * 48 + ot * 16;
    const int sec = colbase >> 6;
    const int grow = sec * DIMC + h * HD + (colbase & 63);
    wbase[ot] = wc + (size_t)(grow >> 4) * ROWTILE_U16 + (l << 3);
  }
  const int atile0 = (b * SEQ + chunk * CHTOK) >> 4;

  for (int sub = 0; sub < 8; ++sub) {
    const u16* abase[4];
    #pragma unroll
    for (int tt = 0; tt < 4; ++tt)
      abase[tt] = xc + (size_t)(atile0 + sub * 4 + tt) * ROWTILE_U16 + (l << 3);

    f32x4 acc[4][3];
    #pragma unroll
    for (int tt = 0; tt < 4; ++tt)
      #pragma unroll
      for (int ot = 0; ot < 3; ++ot)
        acc[tt][ot] = (f32x4){0.f, 0.f, 0.f, 0.f};

    for (int kt = 0; kt < KT; ++kt) {
      const int off = kt * TILE_U16;
      short8 bh_[3], bl_[3];
      #pragma unroll
      for (int ot = 0; ot < 3; ++ot) {
        bh_[ot] = *(const short8*)(wbase[ot] + off);
        bl_[ot] = *(const short8*)(wbase[ot] + off + 512);
      }
      #pragma unroll
      for (int tt = 0; tt < 4; ++tt) {
        short8 ah = *(const short8*)(abase[tt] + off);
        short8 al = *(const short8*)(abase[tt] + off + 512);
        #pragma unroll
        for (int ot = 0; ot < 3; ++ot) {
          acc[tt][ot] = __builtin_amdgcn_mfma_f32_16x16x32_bf16(ah, bh_[ot], acc[tt][ot], 0, 0, 0);
          acc[tt][ot] = __builtin_amdgcn_mfma_f32_16x16x32_bf16(ah, bl_[ot], acc[tt][ot], 0, 0, 0);
          acc[tt][ot] = __builtin_amdgcn_mfma_f32_16x16x32_bf16(al, bh_[ot], acc[tt][ot], 0, 0, 0);
        }
      }
    }
    // scatter k,v to bf16 hi/lo fragment tiles + dsum.
    // element (rr, t): tile = (rr>>4)*2 + (t>>5); lane' = (rr&15)|(((t>>3)&3)<<4)
    __syncthreads();   // prev sub's kv-MFMA reads done -> LDS writable
    #pragma unroll
    for (int ot = 0; ot < 3; ++ot) {
      const int colbase = w * 48 + ot * 16;
      const int col = colbase + lr16;
      if (colbase < 64) {            // q: |sum| only
        #pragma unroll
        for (int tt = 0; tt < 4; ++tt)
          #pragma unroll
          for (int r = 0; r < 4; ++r)
            dsum[ot] += fabsf(acc[tt][ot][r]);
      } else {
        const bool isk = colbase < 128;
        const int rr = col - (isk ? 64 : 128);
        const int region = isk ? 0 : 8192;
        #pragma unroll
        for (int tt = 0; tt < 4; ++tt)
          #pragma unroll
          for (int r = 0; r < 4; ++r) {
            const int t = tt * 16 + cg * 4 + r;
            const float v = acc[tt][ot][r];
            if (isk) dsum[ot] += fabsf(v);
            const u16 hh = bf16_rne(v);
            const float res = v - __uint_as_float(((u32)hh) << 16);
            const u16 ll = bf16_rne(res);
            const int pos = region + ((rr >> 4) * 2 + (t >> 5)) * TILE_U16 +
                            (((rr & 15) | (((t >> 3) & 3) << 4)) << 3) + (t & 7);
            lds16[pos]       = hh;
            lds16[pos + 512] = ll;
          }
      }
    }
    __syncthreads();
    // kv MFMA: wave w owns d-tile w (rows w*16..+16), all 4 e-tiles, K=64
    {
      const u16* At = lds16 + w * 2 * TILE_U16;
      const u16* Bt = lds16 + 8192;
      #pragma unroll
      for (int t2 = 0; t2 < 2; ++t2) {
        short8 kah = *(const short8*)(At + t2 * TILE_U16 + (l << 3));
        short8 kal = *(const short8*)(At + t2 * TILE_U16 + 512 + (l << 3));
        #pragma unroll
        for (int et = 0; et < 4; ++et) {
          short8 vbh = *(const short8*)(Bt + (et * 2 + t2) * TILE_U16 + (l << 3));
          short8 vbl = *(const short8*)(Bt + (et * 2 + t2) * TILE_U16 + 512 + (l << 3));
          kvacc[et] = __builtin_amdgcn_mfma_f32_16x16x32_bf16(kah, vbh, kvacc[et], 0, 0, 0);
          kvacc[et] = __builtin_amdgcn_mfma_f32_16x16x32_bf16(kah, vbl, kvacc[et], 0, 0, 0);
          kvacc[et] = __builtin_amdgcn_mfma_f32_16x16x32_bf16(kal, vbh, kvacc[et], 0, 0, 0);
        }
      }
    }
  }
  // write kv partial: d = w*16 + cg*4 + r, e = et*16 + lr16
  float* ob = kvp + (size_t)si * (HD * HD);
  #pragma unroll
  for (int et = 0; et < 4; ++et)
    #pragma unroll
    for (int r = 0; r < 4; ++r)
      ob[(w * 16 + cg * 4 + r) * HD + et * 16 + lr16] = kvacc[et][r];
  // dq/dk reduction
  __syncthreads();
  #pragma unroll
  for (int ot = 0; ot < 3; ++ot) {
    const int colbase = w * 48 + ot * 16;
    const int col = colbase + lr16;
    if (colbase < 64)        red[col * 4 + cg]              = dsum[ot];
    else if (colbase < 128)  red[256 + (col - 64) * 4 + cg] = dsum[ot];
  }
  __syncthreads();
  if (tid < 64) {
    dqp[(size_t)si * HD + tid] = red[tid*4] + red[tid*4+1] + red[tid*4+2] + red[tid*4+3];
  } else if (tid < 128) {
    const int d = tid - 64;
    dkp[(size_t)si * HD + d] = red[256 + d*4] + red[256 + d*4+1] + red[256 + d*4+2] + red[256 + d*4+3];
  }
}

// ---------------------------------------------------------------------------
__global__ __launch_bounds__(256)
void kv_reduce(const float* __restrict__ kvp, const float* __restrict__ dqp,
               const float* __restrict__ dkp, float* __restrict__ kvs) {
  const int bh = blockIdx.x;
  const int tid = threadIdx.x;
  __shared__ float dqL[64], dkL[64];
  if (tid < 64) {
    float s = 0.f;
    #pragma unroll
    for (int c = 0; c < NCHUNK; ++c) s += dqp[((size_t)bh * NCHUNK + c) * HD + tid];
    dqL[tid] = fmaxf(s, EPSN);
  } else if (tid < 128) {
    const int d = tid - 64;
    float s = 0.f;
    #pragma unroll
    for (int c = 0; c < NCHUNK; ++c) s += dkp[((size_t)bh * NCHUNK + c) * HD + d];
    dkL[d] = fmaxf(s, EPSN);
  }
  __syncthreads();
  #pragma unroll
  for (int i = 0; i < 16; ++i) {
    const int idx = i * 256 + tid;
    const int d = idx >> 6;
    float s = 0.f;
    #pragma unroll
    for (int c = 0; c < NCHUNK; ++c)
      s += kvp[((size_t)bh * NCHUNK + c) * (HD * HD) + idx];
    kvs[(size_t)bh * (HD * HD) + idx] = s / (dqL[d] * dkL[d]);
  }
}

// ---------------------------------------------------------------------------
// W2T[b][c][h*64+d] = sum_e kvs[bh][d][e] * w_proj[c][h*64+e]  (TRANSPOSED
// store vs R10 — so W2T rows are c with k=hd contiguous, ready for split)
// ---------------------------------------------------------------------------
__global__ __launch_bounds__(256)
void w2_kernel(const float* __restrict__ kvs, const float* __restrict__ w_proj,
               float* __restrict__ W2T) {
  const int bh = blockIdx.x;
  const int b = bh / HEADS, h = bh % HEADS;
  const int c0 = blockIdx.y * 128;
  const int tid = threadIdx.x;
  const int tx = tid & 15, ty = tid >> 4;
  __shared__ float KVe[64][68];
  __shared__ float Wp[64][132];
  #pragma unroll
  for (int i = 0; i < 4; ++i) {
    const int idx = i * 256 + tid;
    const int d  = idx >> 4;
    const int e4 = (idx & 15) << 2;
    float4 v4 = *(const float4*)&kvs[(size_t)bh * (HD*HD) + (size_t)d * HD + e4];
    KVe[e4+0][d] = v4.x; KVe[e4+1][d] = v4.y;
    KVe[e4+2][d] = v4.z; KVe[e4+3][d] = v4.w;
  }
  {
    const int c = tid >> 1, half = tid & 1;
    #pragma unroll
    for (int j = 0; j < 8; ++j) {
      const int e = half * 32 + j * 4;
      float4 v4 = *(const float4*)&w_proj[(size_t)(c0 + c) * DIMC + h * HD + e];
      Wp[e+0][c] = v4.x; Wp[e+1][c] = v4.y; Wp[e+2][c] = v4.z; Wp[e+3][c] = v4.w;
    }
  }
  __syncthreads();
  float acc[4][8] = {};
  for (int e = 0; e < 64; ++e) {
    float4 a4 = *(const float4*)&KVe[e][ty << 2];
    float4 b0 = *(const float4*)&Wp[e][tx << 3];
    float4 b1 = *(const float4*)&Wp[e][(tx << 3) + 4];
    float ar[4] = {a4.x, a4.y, a4.z, a4.w};
    float br[8] = {b0.x,b0.y,b0.z,b0.w,b1.x,b1.y,b1.z,b1.w};
    #pragma unroll
    for (int i = 0; i < 4; ++i)
      #pragma unroll
      for (int j = 0; j < 8; ++j)
        acc[i][j] = fmaf(ar[i], br[j], acc[i][j]);
  }
  float* W2Tb = W2T + (size_t)b * DIMC * DIMC;
  #pragma unroll
  for (int j = 0; j < 8; ++j)
    *(float4*)&W2Tb[(size_t)(c0 + (tx << 3) + j) * DIMC + h * HD + (ty << 2)] =
        make_float4(acc[0][j], acc[1][j], acc[2][j], acc[3][j]);
}

// ---------------------------------------------------------------------------
// W3T[b][c][m] = sum_k W2T[b][c][k] * Wq^T[m][k]   (MFMA bf16x3)
// A-frags from w2c (rows c, k=hd), B-frags from wqt (rows m, k=hd).
// grid (12 c-tiles, 4 m-groups, 8 b); per block 64 c x 192 m.
// ---------------------------------------------------------------------------
__global__ __launch_bounds__(256)
void w3t_mfma(const u16* __restrict__ w2c, const u16* __restrict__ wqt,
              float* __restrict__ W3T) {
  const int tid = threadIdx.x;
  const int w = tid >> 6, l = tid & 63;
  const int lr16 = l & 15, cg = l >> 4;
  const int cx = blockIdx.x, my = blockIdx.y, b = blockIdx.z;

  const u16* wbase[3];
  #pragma unroll
  for (int ot = 0; ot < 3; ++ot)
    wbase[ot] = wqt + (size_t)(my * 12 + w * 3 + ot) * ROWTILE_U16 + (l << 3);
  const u16* abase[4];
  #pragma unroll
  for (int tt = 0; tt < 4; ++tt)
    abase[tt] = w2c + (size_t)(b * 48 + cx * 4 + tt) * ROWTILE_U16 + (l << 3);

  f32x4 acc[4][3];
  #pragma unroll
  for (int tt = 0; tt < 4; ++tt)
    #pragma unroll
    for (int ot = 0; ot < 3; ++ot)
      acc[tt][ot] = (f32x4){0.f, 0.f, 0.f, 0.f};

  for (int kt = 0; kt < KT; ++kt) {
    const int off = kt * TILE_U16;
    short8 bh_[3], bl_[3];
    #pragma unroll
    for (int ot = 0; ot < 3; ++ot) {
      bh_[ot] = *(const short8*)(wbase[ot] + off);
      bl_[ot] = *(const short8*)(wbase[ot] + off + 512);
    }
    #pragma unroll
    for (int tt = 0; tt < 4; ++tt) {
      short8 ah = *(const short8*)(abase[tt] + off);
      short8 al = *(const short8*)(abase[tt] + off + 512);
      #pragma unroll
      for (int ot = 0; ot < 3; ++ot) {
        acc[tt][ot] = __builtin_amdgcn_mfma_f32_16x16x32_bf16(ah, bh_[ot], acc[tt][ot], 0, 0, 0);
        acc[tt][ot] = __builtin_amdgcn_mfma_f32_16x16x32_bf16(ah, bl_[ot], acc[tt][ot], 0, 0, 0);
        acc[tt][ot] = __builtin_amdgcn_mfma_f32_16x16x32_bf16(al, bh_[ot], acc[tt][ot], 0, 0, 0);
      }
    }
  }
  float* Wb = W3T + (size_t)b * DIMC * DIMC;
  #pragma unroll
  for (int ot = 0; ot < 3; ++ot) {
    const int col = my * 192 + w * 48 + ot * 16 + lr16;
    #pragma unroll
    for (int tt = 0; tt < 4; ++tt) {
      const int row0 = cx * 64 + tt * 16 + cg * 4;
      #pragma unroll
      for (int r = 0; r < 4; ++r)
        Wb[(size_t)(row0 + r) * DIMC + col] = acc[tt][ot][r];
    }
  }
}

// ---------------------------------------------------------------------------
// out[b][n][c] = sum_m x[b][n][m] * W3T[b][c][m] + bias[c]  (unchanged R10)
// ---------------------------------------------------------------------------
__global__ __launch_bounds__(256)
void final_gemm_mfma(const u16* __restrict__ xc, const u16* __restrict__ w3c,
                     const float* __restrict__ bias, float* __restrict__ out) {
  const int tid = threadIdx.x;
  const int w = tid >> 6, l = tid & 63;
  const int lr16 = l & 15, cg = l >> 4;
  const int ntile = blockIdx.x;
  const int c0 = blockIdx.y * 192;
  const int b = ntile >> 6;
  const int colbase0 = c0 + w * 48;

  const u16* wbase[3];
  #pragma unroll
  for (int ot = 0; ot < 3; ++ot) {
    const int c = colbase0 + ot * 16;
    wbase[ot] = w3c + (size_t)(b * (DIMC/16) + (c >> 4)) * ROWTILE_U16 + (l << 3);
  }
  const u16* abase[4];
  #pragma unroll
  for (int tt = 0; tt < 4; ++tt)
    abase[tt] = xc + (size_t)(ntile * 4 + tt) * ROWTILE_U16 + (l << 3);

  f32x4 acc[4][3];
  #pragma unroll
  for (int tt = 0; tt < 4; ++tt)
    #pragma unroll
    for (int ot = 0; ot < 3; ++ot)
      acc[tt][ot] = (f32x4){0.f, 0.f, 0.f, 0.f};

  for (int kt = 0; kt < KT; ++kt) {
    const int off = kt * TILE_U16;
    short8 bh_[3], bl_[3];
    #pragma unroll
    for (int ot = 0; ot < 3; ++ot) {
      bh_[ot] = *(const short8*)(wbase[ot] + off);
      bl_[ot] = *(const short8*)(wbase[ot] + off + 512);
    }
    #pragma unroll
    for (int tt = 0; tt < 4; ++tt) {
      short8 ah = *(const short8*)(abase[tt] + off);
      short8 al = *(const short8*)(abase[tt] + off + 512);
      #pragma unroll
      for (int ot = 0; ot < 3; ++ot) {
        acc[tt][ot] = __builtin_amdgcn_mfma_f32_16x16x32_bf16(ah, bh_[ot], acc[tt][ot], 0, 0, 0);
        acc[tt][ot] = __builtin_amdgcn_mfma_f32_16x16x32_bf16(ah, bl_[ot], acc[tt][ot], 0, 0, 0);
        acc[tt][ot] = __builtin_amdgcn_mfma_f32_16x16x32_bf16(al, bh_[ot], acc[tt][ot], 0, 0, 0);
      }
    }
  }
  #pragma unroll
  for (int ot = 0; ot < 3; ++ot) {
    const int col = colbase0 + ot * 16 + lr16;
    const float bv = bias[col];
    #pragma unroll
    for (int tt = 0; tt < 4; ++tt) {
      const size_t row0 = (size_t)ntile * 64 + tt * 16 + cg * 4;
      #pragma unroll
      for (int r = 0; r < 4; ++r)
        out[(row0 + r) * DIMC + col] = acc[tt][ot][r] + bv;
    }
  }
}

// ---------------------------------------------------------------------------
extern "C" void kernel_launch(void* const* d_in, const int* in_sizes, int n_in,
                              void* d_out, int out_size, void* d_ws, size_t ws_size,
                              hipStream_t stream) {
  const float* x      = (const float*)d_in[0];
  const float* w_qkv  = (const float*)d_in[1];
  const float* w_proj = (const float*)d_in[2];
  const float* b_proj = (const float*)d_in[3];
  float* out = (float*)d_out;
  float* ws  = (float*)d_ws;

  // workspace layout (WBUF holds W2T first, then is reused for W3T)
  const size_t KVP_SZ = (size_t)BHN * NCHUNK * HD * HD;
  const size_t DQP_SZ = (size_t)BHN * NCHUNK * HD;
  const size_t KVS_SZ = (size_t)BHN * HD * HD;
  const size_t W_SZ   = (size_t)BATCH * DIMC * DIMC;
  const size_t XC_U16  = (size_t)(MTOK/16) * ROWTILE_U16;
  const size_t WC_U16  = (size_t)(THREEC/16) * ROWTILE_U16;
  const size_t WQT_U16 = (size_t)(DIMC/16) * ROWTILE_U16;
  const size_t W2C_U16 = (size_t)(BATCH*DIMC/16) * ROWTILE_U16;
  const size_t W3C_U16 = (size_t)(BATCH*DIMC/16) * ROWTILE_U16;
  float* kvp  = ws;
  float* dqp  = kvp + KVP_SZ;
  float* dkp  = dqp + DQP_SZ;
  float* kvs  = dkp + DQP_SZ;
  float* WBUF = kvs + KVS_SZ;
  u16*   xc   = (u16*)(WBUF + W_SZ);
  u16*   wc   = xc + XC_U16;
  u16*   wqt  = wc + WC_U16;
  u16*   w2c  = wqt + WQT_U16;
  u16*   w3c  = w2c + W2C_U16;
  const size_t need_bytes =
      (KVP_SZ + 2*DQP_SZ + KVS_SZ + W_SZ) * sizeof(float) +
      (XC_U16 + WC_U16 + WQT_U16 + W2C_U16 + W3C_U16) * sizeof(u16);
  if (ws_size < need_bytes) return;   // clean validation failure, not a fault

  const dim3 blk(256);
  // 0) split x, w_qkv, w_qkv_q^T into fragment tiles
  split_tiles<<<dim3((MTOK/16) * KT / 4), blk, 0, stream>>>(x, xc, MTOK/16);
  split_tiles<<<dim3((THREEC/16) * KT / 4), blk, 0, stream>>>(w_qkv, wc, THREEC/16);
  split_tiles_t<<<dim3((DIMC/16) * KT / 4), blk, 0, stream>>>(w_qkv, wqt, DIMC/16, DIMC);
  // 1) fused qkv GEMM + |q|,|k| sums + MFMA kv outer product
  qkv_stage1<<<dim3(BHN * NCHUNK), blk, 0, stream>>>(xc, wc, kvp, dqp, dkp);
  // 2) reduce partials + fold denominators
  kv_reduce<<<dim3(BHN), blk, 0, stream>>>(kvp, dqp, dkp, kvs);
  // 3) W2T (transposed store)
  w2_kernel<<<dim3(BHN, DIMC/128), blk, 0, stream>>>(kvs, w_proj, WBUF);
  // 4) split W2T -> w2c
  split_tiles<<<dim3((BATCH*DIMC/16) * KT / 4), blk, 0, stream>>>(WBUF, w2c, BATCH*DIMC/16);
  // 5) W3T = W2T x Wq^T (MFMA bf16x3), overwrites WBUF
  w3t_mfma<<<dim3(DIMC/64, DIMC/192, BATCH), blk, 0, stream>>>(w2c, wqt, WBUF);
  // 6) split W3T -> w3c
  split_tiles<<<dim3((BATCH*DIMC/16) * KT / 4), blk, 0, stream>>>(WBUF, w3c, BATCH*DIMC/16);
  // 7) out = x @ W3^T + bias
  final_gemm_mfma<<<dim3(MTOK/64, DIMC/192), blk, 0, stream>>>(xc, w3c, b_proj, out);
}

// Round 12
// 571.642 us; speedup vs baseline: 10.6402x; 1.0082x over previous
//
#include <hip/hip_runtime.h>
#include <cstddef>
#include <cstdint>

#define DIMC   768
#define HEADS  12
#define HD     64
#define BATCH  8
#define SEQ    4096
#define MTOK   (BATCH*SEQ)     // 32768
#define THREEC (3*DIMC)        // 2304
#define BHN    (BATCH*HEADS)   // 96
#define NCHUNK 8               // token chunks per (b,h)
#define CHTOK  (SEQ/NCHUNK)    // 512 tokens per chunk
#define EPSN   1e-12f
#define KT     (DIMC/32)       // 24 k-tiles
#define TILE_U16 1024          // one (16-row x 32-k) tile: hi 512 + lo 512 u16
#define ROWTILE_U16 (KT*TILE_U16)  // 24576 u16 per 16-row block

typedef unsigned short u16;
typedef unsigned int   u32;
typedef __attribute__((ext_vector_type(8))) short short8;   // 8 bf16 (4 VGPR)
typedef __attribute__((ext_vector_type(4))) float f32x4;

__device__ inline u16 bf16_rne(float f) {
  u32 u = __float_as_uint(f);
  u32 r = u + 0x7fffu + ((u >> 16) & 1u);
  return (u16)(r >> 16);
}

// packed f32x2 -> bf16x2 (low16 = cvt(a), high16 = cvt(b)); gfx950 HW RNE
__device__ inline u32 cvt_pk_bf16(float a, float b) {
  u32 r;
  asm("v_cvt_pk_bf16_f32 %0, %1, %2" : "=v"(r) : "v"(a), "v"(b));
  return r;
}

// ---------------------------------------------------------------------------
// Split fp32 [R][768] row-major -> bf16 hi/lo in MFMA-FRAGMENT-TILE order.
// Tile (16 rows x 32 k): lane l piece (row=l&15, k=(l>>4)*8..+8) at +l*8 (hi),
// +512+l*8 (lo) -> fragment loads are 64 lanes x contiguous 16B: COALESCED.
// ---------------------------------------------------------------------------
__global__ __launch_bounds__(256)
void split_tiles(const float* __restrict__ in, u16* __restrict__ outp,
                 int nrowtiles) {
  const int l = threadIdx.x & 63;
  const int ntiles = nrowtiles * KT;
  for (int gw = (blockIdx.x * 256 + threadIdx.x) >> 6; gw < ntiles;
       gw += (gridDim.x * 256) >> 6) {
    const int rt = gw / KT, kt = gw % KT;
    const float* src = in + (size_t)(rt * 16 + (l & 15)) * DIMC + kt * 32 + (l >> 4) * 8;
    float4 x0 = *(const float4*)src;
    float4 x1 = *(const float4*)(src + 4);
    float xs[8] = {x0.x, x0.y, x0.z, x0.w, x1.x, x1.y, x1.z, x1.w};
    u32 hw[4], lw[4];
    #pragma unroll
    for (int i = 0; i < 4; ++i) {
      u16 h0 = bf16_rne(xs[2*i]);
      u16 h1 = bf16_rne(xs[2*i+1]);
      float r0 = xs[2*i]   - __uint_as_float(((u32)h0) << 16);
      float r1 = xs[2*i+1] - __uint_as_float(((u32)h1) << 16);
      u16 l0 = bf16_rne(r0);
      u16 l1 = bf16_rne(r1);
      hw[i] = (u32)h0 | ((u32)h1 << 16);
      lw[i] = (u32)l0 | ((u32)l1 << 16);
    }
    u16* tb = outp + (size_t)gw * TILE_U16;
    *(uint4*)(tb + l * 8)       = make_uint4(hw[0], hw[1], hw[2], hw[3]);
    *(uint4*)(tb + 512 + l * 8) = make_uint4(lw[0], lw[1], lw[2], lw[3]);
  }
}

// ---------------------------------------------------------------------------
// Transposed split: source element (row rr, k kk) = in[kk*ld + rr].
// ---------------------------------------------------------------------------
__global__ __launch_bounds__(256)
void split_tiles_t(const float* __restrict__ in, u16* __restrict__ outp,
                   int nrowtiles, int ld) {
  const int l = threadIdx.x & 63;
  const int ntiles = nrowtiles * KT;
  for (int gw = (blockIdx.x * 256 + threadIdx.x) >> 6; gw < ntiles;
       gw += (gridDim.x * 256) >> 6) {
    const int rt = gw / KT, kt = gw % KT;
    const int m = rt * 16 + (l & 15);
    const int k0 = kt * 32 + (l >> 4) * 8;
    float xs[8];
    #pragma unroll
    for (int j = 0; j < 8; ++j) xs[j] = in[(size_t)(k0 + j) * ld + m];
    u32 hw[4], lw[4];
    #pragma unroll
    for (int i = 0; i < 4; ++i) {
      u16 h0 = bf16_rne(xs[2*i]);
      u16 h1 = bf16_rne(xs[2*i+1]);
      float r0 = xs[2*i]   - __uint_as_float(((u32)h0) << 16);
      float r1 = xs[2*i+1] - __uint_as_float(((u32)h1) << 16);
      u16 l0 = bf16_rne(r0);
      u16 l1 = bf16_rne(r1);
      hw[i] = (u32)h0 | ((u32)h1 << 16);
      lw[i] = (u32)l0 | ((u32)l1 << 16);
    }
    u16* tb = outp + (size_t)gw * TILE_U16;
    *(uint4*)(tb + l * 8)       = make_uint4(hw[0], hw[1], hw[2], hw[3]);
    *(uint4*)(tb + 512 + l * 8) = make_uint4(lw[0], lw[1], lw[2], lw[3]);
  }
}

// ---------------------------------------------------------------------------
// Stage 1: qkv GEMM (MFMA bf16x3) + |q|,|k| sums + MFMA kv outer product.
// BALANCED wave->column mapping: wave w owns cols {w*16 (q), 64+w*16 (k),
// 128+w*16 (v)} -> every wave does 1 q-dsum + 1 k-(dsum+scatter) + 1
// v-scatter. Scatter uses v_cvt_pk_bf16_f32 pairs + packed ds_write_b64.
// ---------------------------------------------------------------------------
__global__ __launch_bounds__(256)
void qkv_stage1(const u16* __restrict__ xc, const u16* __restrict__ wc,
                float* __restrict__ kvp, float* __restrict__ dqp,
                float* __restrict__ dkp) {
  const int bid = blockIdx.x;
  const int h = bid % HEADS;
  const int bc = bid / HEADS;
  const int b = bc >> 3, chunk = bc & 7;
  const int bh = b * HEADS + h;
  const int si = bh * NCHUNK + chunk;

  const int tid = threadIdx.x;
  const int w = tid >> 6, l = tid & 63;
  const int lr16 = l & 15, cg = l >> 4;

  __shared__ __align__(16) unsigned char smem[33792];
  u16* lds16 = (u16*)smem;        // k^T tiles [0,8192) u16, v tiles [8192,16384)
  float* red = (float*)smem;      // epilogue scratch

  f32x4 kvacc[4] = {(f32x4){0,0,0,0},(f32x4){0,0,0,0},(f32x4){0,0,0,0},(f32x4){0,0,0,0}};
  float dsum_q = 0.f, dsum_k = 0.f;

  // B-frag bases: section ot (q/k/v), rows ot*DIMC + h*64 + w*16 .. +16
  const u16* wbase[3];
  #pragma unroll
  for (int ot = 0; ot < 3; ++ot) {
    const int grow = ot * DIMC + h * HD + w * 16;
    wbase[ot] = wc + (size_t)(grow >> 4) * ROWTILE_U16 + (l << 3);
  }
  const int atile0 = (b * SEQ + chunk * CHTOK) >> 4;

  for (int sub = 0; sub < 8; ++sub) {
    const u16* abase[4];
    #pragma unroll
    for (int tt = 0; tt < 4; ++tt)
      abase[tt] = xc + (size_t)(atile0 + sub * 4 + tt) * ROWTILE_U16 + (l << 3);

    f32x4 acc[4][3];
    #pragma unroll
    for (int tt = 0; tt < 4; ++tt)
      #pragma unroll
      for (int ot = 0; ot < 3; ++ot)
        acc[tt][ot] = (f32x4){0.f, 0.f, 0.f, 0.f};

    for (int kt = 0; kt < KT; ++kt) {
      const int off = kt * TILE_U16;
      short8 bh_[3], bl_[3];
      #pragma unroll
      for (int ot = 0; ot < 3; ++ot) {
        bh_[ot] = *(const short8*)(wbase[ot] + off);
        bl_[ot] = *(const short8*)(wbase[ot] + off + 512);
      }
      #pragma unroll
      for (int tt = 0; tt < 4; ++tt) {
        short8 ah = *(const short8*)(abase[tt] + off);
        short8 al = *(const short8*)(abase[tt] + off + 512);
        #pragma unroll
        for (int ot = 0; ot < 3; ++ot) {
          acc[tt][ot] = __builtin_amdgcn_mfma_f32_16x16x32_bf16(ah, bh_[ot], acc[tt][ot], 0, 0, 0);
          acc[tt][ot] = __builtin_amdgcn_mfma_f32_16x16x32_bf16(ah, bl_[ot], acc[tt][ot], 0, 0, 0);
          acc[tt][ot] = __builtin_amdgcn_mfma_f32_16x16x32_bf16(al, bh_[ot], acc[tt][ot], 0, 0, 0);
        }
      }
    }
    // --- scatter phase (balanced): q -> dsum; k -> dsum + tiles; v -> tiles
    __syncthreads();   // prev sub's kv-MFMA reads done -> LDS writable
    // q: column w*16+lr16
    #pragma unroll
    for (int tt = 0; tt < 4; ++tt) {
      dsum_q += fabsf(acc[tt][0][0]);
      dsum_q += fabsf(acc[tt][0][1]);
      dsum_q += fabsf(acc[tt][0][2]);
      dsum_q += fabsf(acc[tt][0][3]);
    }
    // k (sec=1, region 0) and v (sec=2, region 8192)
    #pragma unroll
    for (int sec = 1; sec < 3; ++sec) {
      const int region = (sec == 1) ? 0 : 8192;
      #pragma unroll
      for (int tt = 0; tt < 4; ++tt) {
        const float v0 = acc[tt][sec][0], v1 = acc[tt][sec][1];
        const float v2 = acc[tt][sec][2], v3 = acc[tt][sec][3];
        if (sec == 1) {
          dsum_k += fabsf(v0);
          dsum_k += fabsf(v1);
          dsum_k += fabsf(v2);
          dsum_k += fabsf(v3);
        }
        const u32 ph01 = cvt_pk_bf16(v0, v1);
        const u32 ph23 = cvt_pk_bf16(v2, v3);
        const float r0 = v0 - __uint_as_float(ph01 << 16);
        const float r1 = v1 - __uint_as_float(ph01 & 0xffff0000u);
        const float r2 = v2 - __uint_as_float(ph23 << 16);
        const float r3 = v3 - __uint_as_float(ph23 & 0xffff0000u);
        const u32 pl01 = cvt_pk_bf16(r0, r1);
        const u32 pl23 = cvt_pk_bf16(r2, r3);
        // rr = w*16+lr16 -> tile (w*2 + tt>>1); lane' = lr16 | kblk<<4;
        // elem base (cg&1)*4, 4 consecutive u16 -> one 8B write (hi), one (lo)
        const int pos = region + (w * 2 + (tt >> 1)) * TILE_U16 +
                        ((lr16 | (((tt * 2 + (cg >> 1)) & 3) << 4)) << 3) +
                        ((cg & 1) << 2);
        *(uint2*)(lds16 + pos)       = make_uint2(ph01, ph23);
        *(uint2*)(lds16 + pos + 512) = make_uint2(pl01, pl23);
      }
    }
    __syncthreads();
    // kv MFMA: wave w owns d-tile w (rows w*16..+16), all 4 e-tiles, K=64
    {
      const u16* At = lds16 + w * 2 * TILE_U16;
      const u16* Bt = lds16 + 8192;
      #pragma unroll
      for (int t2 = 0; t2 < 2; ++t2) {
        short8 kah = *(const short8*)(At + t2 * TILE_U16 + (l << 3));
        short8 kal = *(const short8*)(At + t2 * TILE_U16 + 512 + (l << 3));
        #pragma unroll
        for (int et = 0; et < 4; ++et) {
          short8 vbh = *(const short8*)(Bt + (et * 2 + t2) * TILE_U16 + (l << 3));
          short8 vbl = *(const short8*)(Bt + (et * 2 + t2) * TILE_U16 + 512 + (l << 3));
          kvacc[et] = __builtin_amdgcn_mfma_f32_16x16x32_bf16(kah, vbh, kvacc[et], 0, 0, 0);
          kvacc[et] = __builtin_amdgcn_mfma_f32_16x16x32_bf16(kah, vbl, kvacc[et], 0, 0, 0);
          kvacc[et] = __builtin_amdgcn_mfma_f32_16x16x32_bf16(kal, vbh, kvacc[et], 0, 0, 0);
        }
      }
    }
  }
  // write kv partial: d = w*16 + cg*4 + r, e = et*16 + lr16
  float* ob = kvp + (size_t)si * (HD * HD);
  #pragma unroll
  for (int et = 0; et < 4; ++et)
    #pragma unroll
    for (int r = 0; r < 4; ++r)
      ob[(w * 16 + cg * 4 + r) * HD + et * 16 + lr16] = kvacc[et][r];
  // dq/dk reduction: red_q[64][4] @0, red_k[64][4] @256 (one writer per slot)
  __syncthreads();
  red[(w * 16 + lr16) * 4 + cg]       = dsum_q;
  red[256 + (w * 16 + lr16) * 4 + cg] = dsum_k;
  __syncthreads();
  if (tid < 64) {
    dqp[(size_t)si * HD + tid] = red[tid*4] + red[tid*4+1] + red[tid*4+2] + red[tid*4+3];
  } else if (tid < 128) {
    const int d = tid - 64;
    dkp[(size_t)si * HD + d] = red[256 + d*4] + red[256 + d*4+1] + red[256 + d*4+2] + red[256 + d*4+3];
  }
}

// ---------------------------------------------------------------------------
__global__ __launch_bounds__(256)
void kv_reduce(const float* __restrict__ kvp, const float* __restrict__ dqp,
               const float* __restrict__ dkp, float* __restrict__ kvs) {
  const int bh = blockIdx.x;
  const int tid = threadIdx.x;
  __shared__ float dqL[64], dkL[64];
  if (tid < 64) {
    float s = 0.f;
    #pragma unroll
    for (int c = 0; c < NCHUNK; ++c) s += dqp[((size_t)bh * NCHUNK + c) * HD + tid];
    dqL[tid] = fmaxf(s, EPSN);
  } else if (tid < 128) {
    const int d = tid - 64;
    float s = 0.f;
    #pragma unroll
    for (int c = 0; c < NCHUNK; ++c) s += dkp[((size_t)bh * NCHUNK + c) * HD + d];
    dkL[d] = fmaxf(s, EPSN);
  }
  __syncthreads();
  #pragma unroll
  for (int i = 0; i < 16; ++i) {
    const int idx = i * 256 + tid;
    const int d = idx >> 6;
    float s = 0.f;
    #pragma unroll
    for (int c = 0; c < NCHUNK; ++c)
      s += kvp[((size_t)bh * NCHUNK + c) * (HD * HD) + idx];
    kvs[(size_t)bh * (HD * HD) + idx] = s / (dqL[d] * dkL[d]);
  }
}

// ---------------------------------------------------------------------------
// W2T[b][c][h*64+d] = sum_e kvs[bh][d][e] * w_proj[c][h*64+e]
// ---------------------------------------------------------------------------
__global__ __launch_bounds__(256)
void w2_kernel(const float* __restrict__ kvs, const float* __restrict__ w_proj,
               float* __restrict__ W2T) {
  const int bh = blockIdx.x;
  const int b = bh / HEADS, h = bh % HEADS;
  const int c0 = blockIdx.y * 128;
  const int tid = threadIdx.x;
  const int tx = tid & 15, ty = tid >> 4;
  __shared__ float KVe[64][68];
  __shared__ float Wp[64][132];
  #pragma unroll
  for (int i = 0; i < 4; ++i) {
    const int idx = i * 256 + tid;
    const int d  = idx >> 4;
    const int e4 = (idx & 15) << 2;
    float4 v4 = *(const float4*)&kvs[(size_t)bh * (HD*HD) + (size_t)d * HD + e4];
    KVe[e4+0][d] = v4.x; KVe[e4+1][d] = v4.y;
    KVe[e4+2][d] = v4.z; KVe[e4+3][d] = v4.w;
  }
  {
    const int c = tid >> 1, half = tid & 1;
    #pragma unroll
    for (int j = 0; j < 8; ++j) {
      const int e = half * 32 + j * 4;
      float4 v4 = *(const float4*)&w_proj[(size_t)(c0 + c) * DIMC + h * HD + e];
      Wp[e+0][c] = v4.x; Wp[e+1][c] = v4.y; Wp[e+2][c] = v4.z; Wp[e+3][c] = v4.w;
    }
  }
  __syncthreads();
  float acc[4][8] = {};
  for (int e = 0; e < 64; ++e) {
    float4 a4 = *(const float4*)&KVe[e][ty << 2];
    float4 b0 = *(const float4*)&Wp[e][tx << 3];
    float4 b1 = *(const float4*)&Wp[e][(tx << 3) + 4];
    float ar[4] = {a4.x, a4.y, a4.z, a4.w};
    float br[8] = {b0.x,b0.y,b0.z,b0.w,b1.x,b1.y,b1.z,b1.w};
    #pragma unroll
    for (int i = 0; i < 4; ++i)
      #pragma unroll
      for (int j = 0; j < 8; ++j)
        acc[i][j] = fmaf(ar[i], br[j], acc[i][j]);
  }
  float* W2Tb = W2T + (size_t)b * DIMC * DIMC;
  #pragma unroll
  for (int j = 0; j < 8; ++j)
    *(float4*)&W2Tb[(size_t)(c0 + (tx << 3) + j) * DIMC + h * HD + (ty << 2)] =
        make_float4(acc[0][j], acc[1][j], acc[2][j], acc[3][j]);
}

// ---------------------------------------------------------------------------
// W3T[b][c][m] = sum_k W2T[b][c][k] * Wq^T[m][k]   (MFMA bf16x3)
// ---------------------------------------------------------------------------
__global__ __launch_bounds__(256)
void w3t_mfma(const u16* __restrict__ w2c, const u16* __restrict__ wqt,
              float* __restrict__ W3T) {
  const int tid = threadIdx.x;
  const int w = tid >> 6, l = tid & 63;
  const int lr16 = l & 15, cg = l >> 4;
  const int cx = blockIdx.x, my = blockIdx.y, b = blockIdx.z;

  const u16* wbase[3];
  #pragma unroll
  for (int ot = 0; ot < 3; ++ot)
    wbase[ot] = wqt + (size_t)(my * 12 + w * 3 + ot) * ROWTILE_U16 + (l << 3);
  const u16* abase[4];
  #pragma unroll
  for (int tt = 0; tt < 4; ++tt)
    abase[tt] = w2c + (size_t)(b * 48 + cx * 4 + tt) * ROWTILE_U16 + (l << 3);

  f32x4 acc[4][3];
  #pragma unroll
  for (int tt = 0; tt < 4; ++tt)
    #pragma unroll
    for (int ot = 0; ot < 3; ++ot)
      acc[tt][ot] = (f32x4){0.f, 0.f, 0.f, 0.f};

  for (int kt = 0; kt < KT; ++kt) {
    const int off = kt * TILE_U16;
    short8 bh_[3], bl_[3];
    #pragma unroll
    for (int ot = 0; ot < 3; ++ot) {
      bh_[ot] = *(const short8*)(wbase[ot] + off);
      bl_[ot] = *(const short8*)(wbase[ot] + off + 512);
    }
    #pragma unroll
    for (int tt = 0; tt < 4; ++tt) {
      short8 ah = *(const short8*)(abase[tt] + off);
      short8 al = *(const short8*)(abase[tt] + off + 512);
      #pragma unroll
      for (int ot = 0; ot < 3; ++ot) {
        acc[tt][ot] = __builtin_amdgcn_mfma_f32_16x16x32_bf16(ah, bh_[ot], acc[tt][ot], 0, 0, 0);
        acc[tt][ot] = __builtin_amdgcn_mfma_f32_16x16x32_bf16(ah, bl_[ot], acc[tt][ot], 0, 0, 0);
        acc[tt][ot] = __builtin_amdgcn_mfma_f32_16x16x32_bf16(al, bh_[ot], acc[tt][ot], 0, 0, 0);
      }
    }
  }
  float* Wb = W3T + (size_t)b * DIMC * DIMC;
  #pragma unroll
  for (int ot = 0; ot < 3; ++ot) {
    const int col = my * 192 + w * 48 + ot * 16 + lr16;
    #pragma unroll
    for (int tt = 0; tt < 4; ++tt) {
      const int row0 = cx * 64 + tt * 16 + cg * 4;
      #pragma unroll
      for (int r = 0; r < 4; ++r)
        Wb[(size_t)(row0 + r) * DIMC + col] = acc[tt][ot][r];
    }
  }
}

// ---------------------------------------------------------------------------
// out[b][n][c] = sum_m x[b][n][m] * W3T[b][c][m] + bias[c]
// ---------------------------------------------------------------------------
__global__ __launch_bounds__(256)
void final_gemm_mfma(const u16* __restrict__ xc, const u16* __restrict__ w3c,
                     const float* __restrict__ bias, float* __restrict__ out) {
  const int tid = threadIdx.x;
  const int w = tid >> 6, l = tid & 63;
  const int lr16 = l & 15, cg = l >> 4;
  const int ntile = blockIdx.x;
  const int c0 = blockIdx.y * 192;
  const int b = ntile >> 6;
  const int colbase0 = c0 + w * 48;

  const u16* wbase[3];
  #pragma unroll
  for (int ot = 0; ot < 3; ++ot) {
    const int c = colbase0 + ot * 16;
    wbase[ot] = w3c + (size_t)(b * (DIMC/16) + (c >> 4)) * ROWTILE_U16 + (l << 3);
  }
  const u16* abase[4];
  #pragma unroll
  for (int tt = 0; tt < 4; ++tt)
    abase[tt] = xc + (size_t)(ntile * 4 + tt) * ROWTILE_U16 + (l << 3);

  f32x4 acc[4][3];
  #pragma unroll
  for (int tt = 0; tt < 4; ++tt)
    #pragma unroll
    for (int ot = 0; ot < 3; ++ot)
      acc[tt][ot] = (f32x4){0.f, 0.f, 0.f, 0.f};

  for (int kt = 0; kt < KT; ++kt) {
    const int off = kt * TILE_U16;
    short8 bh_[3], bl_[3];
    #pragma unroll
    for (int ot = 0; ot < 3; ++ot) {
      bh_[ot] = *(const short8*)(wbase[ot] + off);
      bl_[ot] = *(const short8*)(wbase[ot] + off + 512);
    }
    #pragma unroll
    for (int tt = 0; tt < 4; ++tt) {
      short8 ah = *(const short8*)(abase[tt] + off);
      short8 al = *(const short8*)(abase[tt] + off + 512);
      #pragma unroll
      for (int ot = 0; ot < 3; ++ot) {
        acc[tt][ot] = __builtin_amdgcn_mfma_f32_16x16x32_bf16(ah, bh_[ot], acc[tt][ot], 0, 0, 0);
        acc[tt][ot] = __builtin_amdgcn_mfma_f32_16x16x32_bf16(ah, bl_[ot], acc[tt][ot], 0, 0, 0);
        acc[tt][ot] = __builtin_amdgcn_mfma_f32_16x16x32_bf16(al, bh_[ot], acc[tt][ot], 0, 0, 0);
      }
    }
  }
  #pragma unroll
  for (int ot = 0; ot < 3; ++ot) {
    const int col = colbase0 + ot * 16 + lr16;
    const float bv = bias[col];
    #pragma unroll
    for (int tt = 0; tt < 4; ++tt) {
      const size_t row0 = (size_t)ntile * 64 + tt * 16 + cg * 4;
      #pragma unroll
      for (int r = 0; r < 4; ++r)
        out[(row0 + r) * DIMC + col] = acc[tt][ot][r] + bv;
    }
  }
}

// ---------------------------------------------------------------------------
extern "C" void kernel_launch(void* const* d_in, const int* in_sizes, int n_in,
                              void* d_out, int out_size, void* d_ws, size_t ws_size,
                              hipStream_t stream) {
  const float* x      = (const float*)d_in[0];
  const float* w_qkv  = (const float*)d_in[1];
  const float* w_proj = (const float*)d_in[2];
  const float* b_proj = (const float*)d_in[3];
  float* out = (float*)d_out;
  float* ws  = (float*)d_ws;

  // workspace layout (WBUF holds W2T first, then is reused for W3T)
  const size_t KVP_SZ = (size_t)BHN * NCHUNK * HD * HD;
  const size_t DQP_SZ = (size_t)BHN * NCHUNK * HD;
  const size_t KVS_SZ = (size_t)BHN * HD * HD;
  const size_t W_SZ   = (size_t)BATCH * DIMC * DIMC;
  const size_t XC_U16  = (size_t)(MTOK/16) * ROWTILE_U16;
  const size_t WC_U16  = (size_t)(THREEC/16) * ROWTILE_U16;
  const size_t WQT_U16 = (size_t)(DIMC/16) * ROWTILE_U16;
  const size_t W2C_U16 = (size_t)(BATCH*DIMC/16) * ROWTILE_U16;
  const size_t W3C_U16 = (size_t)(BATCH*DIMC/16) * ROWTILE_U16;
  float* kvp  = ws;
  float* dqp  = kvp + KVP_SZ;
  float* dkp  = dqp + DQP_SZ;
  float* kvs  = dkp + DQP_SZ;
  float* WBUF = kvs + KVS_SZ;
  u16*   xc   = (u16*)(WBUF + W_SZ);
  u16*   wc   = xc + XC_U16;
  u16*   wqt  = wc + WC_U16;
  u16*   w2c  = wqt + WQT_U16;
  u16*   w3c  = w2c + W2C_U16;
  const size_t need_bytes =
      (KVP_SZ + 2*DQP_SZ + KVS_SZ + W_SZ) * sizeof(float) +
      (XC_U16 + WC_U16 + WQT_U16 + W2C_U16 + W3C_U16) * sizeof(u16);
  if (ws_size < need_bytes) return;   // clean validation failure, not a fault

  const dim3 blk(256);
  // 0) split x, w_qkv, w_qkv_q^T into fragment tiles
  split_tiles<<<dim3((MTOK/16) * KT / 4), blk, 0, stream>>>(x, xc, MTOK/16);
  split_tiles<<<dim3((THREEC/16) * KT / 4), blk, 0, stream>>>(w_qkv, wc, THREEC/16);
  split_tiles_t<<<dim3((DIMC/16) * KT / 4), blk, 0, stream>>>(w_qkv, wqt, DIMC/16, DIMC);
  // 1) fused qkv GEMM + |q|,|k| sums + MFMA kv outer product
  qkv_stage1<<<dim3(BHN * NCHUNK), blk, 0, stream>>>(xc, wc, kvp, dqp, dkp);
  // 2) reduce partials + fold denominators
  kv_reduce<<<dim3(BHN), blk, 0, stream>>>(kvp, dqp, dkp, kvs);
  // 3) W2T (transposed store)
  w2_kernel<<<dim3(BHN, DIMC/128), blk, 0, stream>>>(kvs, w_proj, WBUF);
  // 4) split W2T -> w2c
  split_tiles<<<dim3((BATCH*DIMC/16) * KT / 4), blk, 0, stream>>>(WBUF, w2c, BATCH*DIMC/16);
  // 5) W3T = W2T x Wq^T (MFMA bf16x3), overwrites WBUF
  w3t_mfma<<<dim3(DIMC/64, DIMC/192, BATCH), blk, 0, stream>>>(w2c, wqt, WBUF);
  // 6) split W3T -> w3c
  split_tiles<<<dim3((BATCH*DIMC/16) * KT / 4), blk, 0, stream>>>(WBUF, w3c, BATCH*DIMC/16);
  // 7) out = x @ W3^T + bias
  final_gemm_mfma<<<dim3(MTOK/64, DIMC/192), blk, 0, stream>>>(xc, w3c, b_proj, out);
}